// Round 21
// baseline (189.655 us; speedup 1.0000x reference)
//
#include <hip/hip_runtime.h>
#include <hip/hip_bf16.h>

typedef __attribute__((ext_vector_type(8))) short short8;
typedef __attribute__((ext_vector_type(4))) short short4b;
typedef __attribute__((ext_vector_type(4))) float f32x4;
typedef unsigned short ushort_t;

#define NTOK 262144   // B*D*H*W = 2*32*64*64

__device__ __forceinline__ ushort_t f2bf(float f){
  __hip_bfloat16 h = __float2bfloat16(f);
  return *reinterpret_cast<ushort_t*>(&h);
}
__device__ __forceinline__ float bf2f(ushort_t u){
  union { unsigned int i; float f; } v; v.i = ((unsigned int)u) << 16; return v.f;
}
// 1-instruction reciprocal (rel err ~2.5e-7)
__device__ __forceinline__ float fast_rcp(float x){
  float r; asm("v_rcp_f32 %0, %1" : "=v"(r) : "v"(x)); return r;
}
// sigmoid-form gelu: x * sigmoid(1.702x) (err <=0.005 for |x|<~1; our pre-act std ~0.2)
__device__ __forceinline__ float gelu_f(float x){
  float e = __expf(-1.702f * x);
  return x * fast_rcp(1.0f + e);
}
// LDS-only barrier: drains lgkm but NOT vmcnt.
__device__ __forceinline__ void bar_lds(){
  asm volatile("s_waitcnt lgkmcnt(0)" ::: "memory");
  __builtin_amdgcn_s_barrier();
  __builtin_amdgcn_sched_barrier(0);
}
// counted-vmcnt barriers (T4)
__device__ __forceinline__ void bar_cnt5(){
  asm volatile("s_waitcnt vmcnt(5) lgkmcnt(0)" ::: "memory");
  __builtin_amdgcn_s_barrier();
  __builtin_amdgcn_sched_barrier(0);
}
__device__ __forceinline__ void bar_cnt0(){
  asm volatile("s_waitcnt vmcnt(0) lgkmcnt(0)" ::: "memory");
  __builtin_amdgcn_s_barrier();
  __builtin_amdgcn_sched_barrier(0);
}
// async global->LDS, 16B per lane
__device__ __forceinline__ void gl_lds16(const ushort_t* g, ushort_t* l){
  __builtin_amdgcn_global_load_lds(
      (const __attribute__((address_space(1))) void*)g,
      (__attribute__((address_space(3))) void*)l, 16, 0, 0);
}

// stage a 48x96 half-slice into [48][104]-padded LDS (624 x 16B units; unit 12
// of each 13-unit row is pad, src = row start, never read). Full-drain use.
__device__ __forceinline__ void stage624(const ushort_t* __restrict__ src,
                                         ushort_t* __restrict__ dst, int tid)
{
  #pragma unroll
  for (int it = 0; it < 3; ++it) {
    int u = tid + it * 256;
    if (u < 624) {
      int row = u / 13, c16 = u % 13;
      const ushort_t* sp = src + row * 96 + ((c16 == 12) ? 0 : c16 * 8);
      gl_lds16(sp, dst + (size_t)(u & ~63) * 8);
    }
  }
}

// mlp2: padded 1280-unit flat buffer (20480B), EXACTLY 5 loads/thread
__device__ __forceinline__ void stage_wp(const ushort_t* __restrict__ src,
                                         int src_stride, ushort_t* __restrict__ dst, int tid)
{
  #pragma unroll
  for (int it = 0; it < 5; ++it) {
    int u = tid + it * 256;
    int row = u / 13, c16 = u % 13;
    const ushort_t* sp = src + row * src_stride + ((c16 >= 12) ? 0 : c16 * 8);
    gl_lds16(sp, dst + (size_t)(u & ~63) * 8);
  }
}

// ---------------- weight prep: fp32 -> bf16, transposed; Q-scale folded ----------------
__global__ __launch_bounds__(256) void prep_kernel(
    const float* __restrict__ wq, const float* __restrict__ wk, const float* __restrict__ wv,
    const float* __restrict__ wo, const float* __restrict__ w1, const float* __restrict__ w2,
    const float* __restrict__ bq, const float* __restrict__ bk, const float* __restrict__ bv,
    ushort_t* __restrict__ Wqkv, ushort_t* __restrict__ Wo,
    ushort_t* __restrict__ W1, ushort_t* __restrict__ W2, float* __restrict__ biasq)
{
  const float qs = 0.20412414523193150818f;   // 1/sqrt(24)
  int i = blockIdx.x * 256 + threadIdx.x;
  if (i < 27648) {                       // Wqkv_t[j][c], j = s*96 + h*24 + d
    int j = i / 96, c = i % 96;
    int s = j / 96, rem = j % 96;
    const float* src = (s == 0) ? wq : (s == 1) ? wk : wv;
    float val = src[c * 96 + rem];
    if (s == 0) val *= qs;               // fold QK^T scale into Q
    Wqkv[j * 96 + c] = f2bf(val);
  } else if (i < 36864) {                // Wo_t[c][hd] = wo[hd][c]
    int ii = i - 27648;
    int c = ii / 96, hd = ii % 96;
    Wo[ii] = f2bf(wo[hd * 96 + c]);
  } else if (i < 73728) {                // W1_t[j][c] = w1[c][j]
    int ii = i - 36864;
    int j = ii / 96, c = ii % 96;
    W1[ii] = f2bf(w1[c * 384 + j]);
  } else if (i < 110592) {               // W2_t[c][j] = w2[j][c]
    int ii = i - 73728;
    int c = ii / 384, j = ii % 384;
    W2[ii] = f2bf(w2[j * 96 + c]);
  } else if (i < 110880) {               // combined qkv bias (fp32), Q part scaled
    int j = i - 110592;
    int s = j / 96, rem = j % 96;
    const float* src = (s == 0) ? bq : (s == 1) ? bk : bv;
    float val = src[rem];
    if (s == 0) val *= qs;
    biasq[j] = val;
  }
}

// ================= FUSED: LN1 + QKV + window attention + proj + residual =================
// LDS diet: 54,272 B -> 3 blocks/CU (12 waves, 3/SIMD). Single half-slice
// weight buffer (full drains, TLP covers); P packed [4][64][64] with XOR-unit
// swizzle overlaid on the dead QK+Ws region.
// Layout (ushort offsets in SM[27136]):
//   0      : QK[64][200] (12,800)  | hbt[64][104] alias | O_lds[64][104] alias
//   0      : P heads [4][64 rows][64 cols, XOR-swz] span 16,384 (over QK+Ws, both dead)
//   12,800 : Ws half-slice [48][104]-padded (5,120)
//   17,920 : Vt[4][32][72] (9,216)
__global__ __launch_bounds__(256, 3) void fat_kernel(
    const float* __restrict__ x, const float* __restrict__ g, const float* __restrict__ b,
    const ushort_t* __restrict__ Wqkv, const float* __restrict__ biasq,
    const ushort_t* __restrict__ Wo, const float* __restrict__ bo,
    ushort_t* __restrict__ x2b)
{
  __shared__ ushort_t SM[27136];
  const int WS_OFF = 12800, VT_OFF = 17920;

  int tid = threadIdx.x;
  int bid = blockIdx.x;
  int n = (bid & 7) * 512 + (bid >> 3);    // bijective XCD swizzle
  int wq_ = n & 15, hq = (n >> 4) & 15, rest = n >> 8;
  int dq = rest & 7, bb_ = rest >> 3;
  int base = bb_ * 131072 + dq * 16384 + hq * 256 + wq_ * 4;
  #define TOK(s) (base + ((s) >> 4) * 4096 + (((s) >> 2) & 3) * 64 + ((s) & 3))

  stage624(Wqkv, SM + WS_OFF, tid);        // Wqkv half 0 flies under LN

  // ---- LN1: thread t -> slot t>>2, quarter t&3 (wave-private hbt rows) ----
  {
    int s = tid >> 2, qr = tid & 3;
    const float* xp = x + (size_t)TOK(s) * 96 + qr * 24;
    f32x4 v[6];
    float sm = 0.f, sq = 0.f;
    #pragma unroll
    for (int i = 0; i < 6; i++) {
      v[i] = *reinterpret_cast<const f32x4*>(xp + i * 4);
      #pragma unroll
      for (int j = 0; j < 4; j++) { sm += v[i][j]; sq += v[i][j] * v[i][j]; }
    }
    sm += __shfl_xor(sm, 1); sq += __shfl_xor(sq, 1);
    sm += __shfl_xor(sm, 2); sq += __shfl_xor(sq, 2);
    float mean = sm * (1.0f / 96.0f);
    float var  = sq * (1.0f / 96.0f) - mean * mean;
    float rstd = rsqrtf(var + 1e-5f);
    #pragma unroll
    for (int i8 = 0; i8 < 3; i8++) {
      short8 pk;
      #pragma unroll
      for (int j = 0; j < 8; j++) {
        int c = qr * 24 + i8 * 8 + j;
        pk[j] = (short)f2bf((v[(i8 * 8 + j) >> 2][(i8 * 8 + j) & 3] - mean) * rstd * g[c] + b[c]);
      }
      *reinterpret_cast<short8*>(&SM[s * 104 + qr * 24 + i8 * 8]) = pk;
    }
  }

  int w = tid >> 6, lane = tid & 63, g16 = lane >> 4, l15 = lane & 15;
  short8 af[3];                            // own-wave hbt rows (in-order LDS)
  #pragma unroll
  for (int ks = 0; ks < 3; ks++)
    af[ks] = *reinterpret_cast<const short8*>(&SM[(w * 16 + l15) * 104 + ks * 32 + g16 * 8]);
  bar_lds();                               // af loads done: QK region (aliases hbt) free

  // ---- QKV: 6 half-slice phases, single buffer, full drains ----
  for (int hidx = 0; hidx < 6; ++hidx) {
    const ushort_t* buf = SM + WS_OFF;
    bar_cnt0();                            // half resident + prev epilogue visible
    f32x4 acc[3];
    #pragma unroll
    for (int jj = 0; jj < 3; jj++) acc[jj] = (f32x4){0.f, 0.f, 0.f, 0.f};
    __builtin_amdgcn_s_setprio(1);
    #pragma unroll
    for (int jj = 0; jj < 3; jj++)
      #pragma unroll
      for (int ks = 0; ks < 3; ks++) {
        short8 wfr = *reinterpret_cast<const short8*>(&buf[(jj * 16 + l15) * 104 + ks * 32 + g16 * 8]);
        acc[jj] = __builtin_amdgcn_mfma_f32_16x16x32_bf16(wfr, af[ks], acc[jj], 0, 0, 0);
      }
    __builtin_amdgcn_s_setprio(0);
    bar_lds();                             // all waves done reading this half
    if (hidx < 5) stage624(Wqkv + (size_t)(hidx + 1) * 4608, SM + WS_OFF, tid);
    int grp = hidx >> 1, half = hidx & 1;
    if (grp < 2) {
      #pragma unroll
      for (int jj = 0; jj < 3; jj++) {
        int c0 = grp * 96 + (half * 3 + jj) * 16 + g16 * 4;
        f32x4 bb4 = *reinterpret_cast<const f32x4*>(&biasq[c0]);
        unsigned lo = (unsigned)f2bf(acc[jj][0] + bb4[0]) | ((unsigned)f2bf(acc[jj][1] + bb4[1]) << 16);
        unsigned hi = (unsigned)f2bf(acc[jj][2] + bb4[2]) | ((unsigned)f2bf(acc[jj][3] + bb4[3]) << 16);
        uint2 pk; pk.x = lo; pk.y = hi;
        *reinterpret_cast<uint2*>(&SM[(w * 16 + l15) * 200 + c0]) = pk;
      }
    } else {
      #pragma unroll
      for (int jj = 0; jj < 3; jj++) {
        int c0 = (half * 3 + jj) * 16 + g16 * 4;
        f32x4 bb4 = *reinterpret_cast<const f32x4*>(&biasq[192 + c0]);
        #pragma unroll
        for (int r = 0; r < 4; r++) {
          int vcol = c0 + r;
          int h2 = vcol / 24, d2 = vcol - h2 * 24;
          SM[VT_OFF + h2 * 2304 + d2 * 72 + (w * 16 + l15)] = f2bf(acc[jj][r] + bb4[r]);
        }
      }
    }
  }
  bar_lds();                               // all QK/Vt epilogue writes visible

  // ---- attention: wave = head ----
  int h = w;
  short8 kf[4], qf[4];
  const short8 z8 = {0, 0, 0, 0, 0, 0, 0, 0};
  #pragma unroll
  for (int i = 0; i < 4; i++) {
    qf[i] = (g16 < 3) ? *(const short8*)&SM[(i * 16 + l15) * 200 + h * 24 + g16 * 8]      : z8;
    kf[i] = (g16 < 3) ? *(const short8*)&SM[(i * 16 + l15) * 200 + 96 + h * 24 + g16 * 8] : z8;
  }
  f32x4 st[4][4];
  __builtin_amdgcn_s_setprio(1);
  #pragma unroll
  for (int tm = 0; tm < 4; tm++)
    #pragma unroll
    for (int tn = 0; tn < 4; tn++)
      st[tm][tn] = __builtin_amdgcn_mfma_f32_16x16x32_bf16(kf[tm], qf[tn],
                    (f32x4){0.f, 0.f, 0.f, 0.f}, 0, 0, 0);
  __builtin_amdgcn_s_setprio(0);
  bar_lds();                               // all QK reads done: P region free

  // softmax + P writes (packed [64][64] per head, XOR-unit swizzle)
  #pragma unroll
  for (int tn = 0; tn < 4; tn++) {
    float m = st[0][tn][0];
    #pragma unroll
    for (int tm = 0; tm < 4; tm++)
      #pragma unroll
      for (int r = 0; r < 4; r++) m = fmaxf(m, st[tm][tn][r]);
    m = fmaxf(m, __shfl_xor(m, 16));
    m = fmaxf(m, __shfl_xor(m, 32));
    float sum = 0.f;
    #pragma unroll
    for (int tm = 0; tm < 4; tm++)
      #pragma unroll
      for (int r = 0; r < 4; r++) {
        float e = __expf(st[tm][tn][r] - m);
        st[tm][tn][r] = e;
        sum += e;
      }
    sum += __shfl_xor(sum, 16);
    sum += __shfl_xor(sum, 32);
    float inv = fast_rcp(sum);
    int q = tn * 16 + l15;
    #pragma unroll
    for (int tm = 0; tm < 4; tm++) {
      unsigned lo = (unsigned)f2bf(st[tm][tn][0] * inv) | ((unsigned)f2bf(st[tm][tn][1] * inv) << 16);
      unsigned hi = (unsigned)f2bf(st[tm][tn][2] * inv) | ((unsigned)f2bf(st[tm][tn][3] * inv) << 16);
      uint2 pk; pk.x = lo; pk.y = hi;
      int u = tm * 2 + (g16 >> 1);         // 16B unit index 0..7
      *reinterpret_cast<uint2*>(&SM[h * 4096 + q * 64 + ((u ^ (q & 7)) << 3) + ((g16 & 1) << 2)]) = pk;
    }
  }

  // ---- O = P @ V (own-head P just written by this wave; in-order LDS) ----
  f32x4 oacc[4][2];
  #pragma unroll
  for (int qt = 0; qt < 4; qt++)
    #pragma unroll
    for (int dt = 0; dt < 2; dt++) oacc[qt][dt] = (f32x4){0.f, 0.f, 0.f, 0.f};
  __builtin_amdgcn_s_setprio(1);
  #pragma unroll
  for (int ks = 0; ks < 2; ks++) {
    short8 vb[2];
    #pragma unroll
    for (int dt = 0; dt < 2; dt++)
      vb[dt] = *(const short8*)&SM[VT_OFF + h * 2304 + (dt * 16 + l15) * 72 + ks * 32 + g16 * 8];
    #pragma unroll
    for (int qt = 0; qt < 4; qt++) {
      int row = qt * 16 + l15;
      int up = ks * 4 + g16;
      short8 pa = *(const short8*)&SM[h * 4096 + row * 64 + ((up ^ (row & 7)) << 3)];
      #pragma unroll
      for (int dt = 0; dt < 2; dt++)
        oacc[qt][dt] = __builtin_amdgcn_mfma_f32_16x16x32_bf16(pa, vb[dt], oacc[qt][dt], 0, 0, 0);
    }
  }
  __builtin_amdgcn_s_setprio(0);

  bar_lds();                               // all P reads done: O/Ws regions free
  stage624(Wo, SM + WS_OFF, tid);          // Wo half 0 flies under O writes
  #pragma unroll
  for (int qt = 0; qt < 4; qt++)
    #pragma unroll
    for (int dt = 0; dt < 2; dt++) {
      int d = dt * 16 + l15;
      if (d < 24) {
        #pragma unroll
        for (int r = 0; r < 4; r++)
          SM[(qt * 16 + g16 * 4 + r) * 104 + h * 24 + d] = f2bf(oacc[qt][dt][r]);
      }
    }
  bar_cnt0();                              // O visible + Wo half 0 resident

  // ---- proj (swapped): lane = token, regs = 4 consecutive outcols ----
  f32x4 pacc[6];
  #pragma unroll
  for (int nt = 0; nt < 6; nt++) pacc[nt] = (f32x4){0.f, 0.f, 0.f, 0.f};
  __builtin_amdgcn_s_setprio(1);
  #pragma unroll
  for (int ks = 0; ks < 3; ks++) {
    short8 pa = *(const short8*)&SM[(w * 16 + l15) * 104 + ks * 32 + g16 * 8];
    #pragma unroll
    for (int nt = 0; nt < 3; nt++) {
      short8 wb = *reinterpret_cast<const short8*>(&SM[WS_OFF + (nt * 16 + l15) * 104 + ks * 32 + g16 * 8]);
      pacc[nt] = __builtin_amdgcn_mfma_f32_16x16x32_bf16(wb, pa, pacc[nt], 0, 0, 0);
    }
  }
  __builtin_amdgcn_s_setprio(0);
  bar_lds();                               // Wo half 0 reads done
  stage624(Wo + 4608, SM + WS_OFF, tid);   // Wo half 1
  bar_cnt0();                              // Wo half 1 resident
  __builtin_amdgcn_s_setprio(1);
  #pragma unroll
  for (int ks = 0; ks < 3; ks++) {
    short8 pa = *(const short8*)&SM[(w * 16 + l15) * 104 + ks * 32 + g16 * 8];
    #pragma unroll
    for (int nt = 0; nt < 3; nt++) {
      short8 wb = *reinterpret_cast<const short8*>(&SM[WS_OFF + (nt * 16 + l15) * 104 + ks * 32 + g16 * 8]);
      pacc[3 + nt] = __builtin_amdgcn_mfma_f32_16x16x32_bf16(wb, pa, pacc[3 + nt], 0, 0, 0);
    }
  }
  __builtin_amdgcn_s_setprio(0);
  {
    size_t t = (size_t)TOK(w * 16 + l15);
    #pragma unroll
    for (int nt = 0; nt < 6; nt++) {
      int c0 = nt * 16 + g16 * 4;
      f32x4 bo4 = *reinterpret_cast<const f32x4*>(&bo[c0]);
      f32x4 xr  = *reinterpret_cast<const f32x4*>(&x[t * 96 + c0]);
      float v0 = pacc[nt][0] + bo4[0] + xr[0];
      float v1 = pacc[nt][1] + bo4[1] + xr[1];
      float v2 = pacc[nt][2] + bo4[2] + xr[2];
      float v3 = pacc[nt][3] + bo4[3] + xr[3];
      unsigned lo = (unsigned)f2bf(v0) | ((unsigned)f2bf(v1) << 16);
      unsigned hi = (unsigned)f2bf(v2) | ((unsigned)f2bf(v3) << 16);
      uint2 pk; pk.x = lo; pk.y = hi;
      *reinterpret_cast<uint2*>(&x2b[t * 96 + c0]) = pk;
    }
  }
  #undef TOK
}

// ---- per-thread half-row LN (bf16 input) into LDS tile smem[128][104] ----
__device__ __forceinline__ void ln_to_lds_b(const ushort_t* __restrict__ xrow_base,
    const float* __restrict__ gg, const float* __restrict__ bb,
    ushort_t (*hbt)[104], int tid)
{
  int row = tid >> 1, half = tid & 1;
  const ushort_t* xp = xrow_base + (size_t)row * 96 + half * 48;
  short8 vv[6];
  #pragma unroll
  for (int i = 0; i < 6; i++) vv[i] = *reinterpret_cast<const short8*>(xp + i * 8);
  float v[48];
  float s = 0.f, sq = 0.f;
  #pragma unroll
  for (int i = 0; i < 6; i++)
    #pragma unroll
    for (int j = 0; j < 8; j++) {
      float f = bf2f((ushort_t)vv[i][j]);
      v[i * 8 + j] = f; s += f; sq += f * f;
    }
  s  += __shfl_xor(s, 1);
  sq += __shfl_xor(sq, 1);
  float mean = s * (1.0f / 96.0f);
  float var  = sq * (1.0f / 96.0f) - mean * mean;
  float rstd = rsqrtf(var + 1e-5f);
  #pragma unroll
  for (int i8 = 0; i8 < 6; i8++) {
    short8 pk;
    #pragma unroll
    for (int j = 0; j < 8; j++) {
      int c = half * 48 + i8 * 8 + j;
      pk[j] = (short)f2bf((v[i8 * 8 + j] - mean) * rstd * gg[c] + bb[c]);
    }
    *reinterpret_cast<short8*>(&hbt[row][half * 48 + i8 * 8]) = pk;
  }
}

// ---------------- fused LN2 + MLP + residual: counted-vmcnt ping-pong (r16 winner) ----------------
__global__ __launch_bounds__(256, 2) void mlp2_kernel(
    const ushort_t* __restrict__ x2b, const float* __restrict__ g, const float* __restrict__ b,
    const ushort_t* __restrict__ W1t, const float* __restrict__ b1,
    const ushort_t* __restrict__ W2t, const float* __restrict__ b2,
    float* __restrict__ out)
{
  __shared__ ushort_t smem[128][104];   // LN rows, then mid (same storage) 26,624 B
  __shared__ ushort_t WsA[10240];       // W1 slice, padded to 1280 units (20,480 B)
  __shared__ ushort_t WsB[10240];       // W2 slice, padded (20,480 B)
  __shared__ float bias1[384];
  __shared__ float bias2[96];
  int tid = threadIdx.x;
  int bid = blockIdx.x;
  int blk = (bid & 7) * 256 + (bid >> 3);   // bijective XCD swizzle
  size_t r0 = (size_t)blk * 128;

  stage_wp(W1t, 96, WsA, tid);          // W1[0] -> A
  stage_wp(W2t, 384, WsB, tid);         // W2[0] -> B
  bias1[tid] = b1[tid];
  if (tid < 128) bias1[256 + tid] = b1[256 + tid];
  if (tid < 96)  bias2[tid] = b2[tid];
  ln_to_lds_b(x2b + r0 * 96, g, b, smem, tid);

  int w = tid >> 6, lane = tid & 63, g16 = lane >> 4, l15 = lane & 15;
  short8 af[2][3];
  #pragma unroll
  for (int mi = 0; mi < 2; mi++)
    #pragma unroll
    for (int ks = 0; ks < 3; ks++)
      af[mi][ks] = *reinterpret_cast<const short8*>(&smem[w * 32 + mi * 16 + l15][ks * 32 + g16 * 8]);
  __builtin_amdgcn_sched_barrier(0);

  f32x4 oacc[6][2];
  #pragma unroll
  for (int nt = 0; nt < 6; nt++) { oacc[nt][0] = (f32x4){0.f,0.f,0.f,0.f}; oacc[nt][1] = (f32x4){0.f,0.f,0.f,0.f}; }

  for (int cc = 0; cc < 4; ++cc) {
    bar_cnt5();                         // A = W1[cc] resident (B's 5 still in flight)
    f32x4 acc[6][2];
    #pragma unroll
    for (int nt = 0; nt < 6; nt++) { acc[nt][0] = (f32x4){0.f,0.f,0.f,0.f}; acc[nt][1] = (f32x4){0.f,0.f,0.f,0.f}; }
    __builtin_amdgcn_s_setprio(1);
    #pragma unroll
    for (int nt = 0; nt < 6; nt++)
      #pragma unroll
      for (int ks = 0; ks < 3; ks++) {
        short8 wfr = *reinterpret_cast<const short8*>(&WsA[(nt * 16 + l15) * 104 + ks * 32 + g16 * 8]);
        acc[nt][0] = __builtin_amdgcn_mfma_f32_16x16x32_bf16(wfr, af[0][ks], acc[nt][0], 0, 0, 0);
        acc[nt][1] = __builtin_amdgcn_mfma_f32_16x16x32_bf16(wfr, af[1][ks], acc[nt][1], 0, 0, 0);
      }
    __builtin_amdgcn_s_setprio(0);
    #pragma unroll
    for (int nt = 0; nt < 6; nt++) {
      f32x4 bb4 = *reinterpret_cast<const f32x4*>(&bias1[cc * 96 + nt * 16 + g16 * 4]);
      #pragma unroll
      for (int mi = 0; mi < 2; mi++) {
        float g0 = gelu_f(acc[nt][mi][0] + bb4[0]);
        float g1 = gelu_f(acc[nt][mi][1] + bb4[1]);
        float g2 = gelu_f(acc[nt][mi][2] + bb4[2]);
        float g3 = gelu_f(acc[nt][mi][3] + bb4[3]);
        unsigned lo = (unsigned)f2bf(g0) | ((unsigned)f2bf(g1) << 16);
        unsigned hi = (unsigned)f2bf(g2) | ((unsigned)f2bf(g3) << 16);
        uint2 pk; pk.x = lo; pk.y = hi;
        *reinterpret_cast<uint2*>(&smem[w * 32 + mi * 16 + l15][nt * 16 + g16 * 4]) = pk;
      }
    }
    short8 a2[2][3];
    #pragma unroll
    for (int mi = 0; mi < 2; mi++)
      #pragma unroll
      for (int ks = 0; ks < 3; ks++)
        a2[mi][ks] = *reinterpret_cast<const short8*>(&smem[w * 32 + mi * 16 + l15][ks * 32 + g16 * 8]);
    bar_lds();                          // all waves done reading A
    if (cc < 3) stage_wp(W1t + (cc + 1) * 9216, 96, WsA, tid);   // W1[cc+1] -> A
    if (cc < 3) bar_cnt5(); else bar_cnt0();   // B = W2[cc] resident (A' in flight)
    __builtin_amdgcn_s_setprio(1);
    #pragma unroll
    for (int nt = 0; nt < 6; nt++)
      #pragma unroll
      for (int ks = 0; ks < 3; ks++) {
        short8 wfr = *reinterpret_cast<const short8*>(&WsB[(nt * 16 + l15) * 104 + ks * 32 + g16 * 8]);
        oacc[nt][0] = __builtin_amdgcn_mfma_f32_16x16x32_bf16(wfr, a2[0][ks], oacc[nt][0], 0, 0, 0);
        oacc[nt][1] = __builtin_amdgcn_mfma_f32_16x16x32_bf16(wfr, a2[1][ks], oacc[nt][1], 0, 0, 0);
      }
    __builtin_amdgcn_s_setprio(0);
    if (cc < 3) {
      bar_lds();                        // all waves done reading B
      stage_wp(W2t + (cc + 1) * 96, 384, WsB, tid);              // W2[cc+1] -> B
    }
  }

  // epilogue: out = oacc + b2 + residual(x2b) (fp32 out)
  #pragma unroll
  for (int nt = 0; nt < 6; nt++) {
    int c0 = nt * 16 + g16 * 4;
    f32x4 bb4 = *reinterpret_cast<const f32x4*>(&bias2[c0]);
    #pragma unroll
    for (int mi = 0; mi < 2; mi++) {
      size_t row = r0 + w * 32 + mi * 16 + l15;
      short4b rr = *reinterpret_cast<const short4b*>(&x2b[row * 96 + c0]);
      f32x4 o;
      #pragma unroll
      for (int r = 0; r < 4; r++) o[r] = oacc[nt][mi][r] + bb4[r] + bf2f((ushort_t)rr[r]);
      *reinterpret_cast<f32x4*>(&out[row * 96 + c0]) = o;
    }
  }
}

// ---------------- launch ----------------
extern "C" void kernel_launch(void* const* d_in, const int* in_sizes, int n_in,
                              void* d_out, int out_size, void* d_ws, size_t ws_size,
                              hipStream_t stream)
{
  (void)in_sizes; (void)n_in; (void)out_size; (void)ws_size;
  const float* x    = (const float*)d_in[0];
  const float* ln1g = (const float*)d_in[1];
  const float* ln1b = (const float*)d_in[2];
  const float* wq   = (const float*)d_in[3];
  const float* bq   = (const float*)d_in[4];
  const float* wk   = (const float*)d_in[5];
  const float* bk   = (const float*)d_in[6];
  const float* wv   = (const float*)d_in[7];
  const float* bv   = (const float*)d_in[8];
  const float* wo   = (const float*)d_in[9];
  const float* bo   = (const float*)d_in[10];
  const float* ln2g = (const float*)d_in[11];
  const float* ln2b = (const float*)d_in[12];
  const float* w1   = (const float*)d_in[13];
  const float* b1   = (const float*)d_in[14];
  const float* w2   = (const float*)d_in[15];
  const float* b2   = (const float*)d_in[16];

  char* ws = (char*)d_ws;
  ushort_t* x2b  = (ushort_t*)(ws);                          // [N,96] bf16  50,331,648 B
  char* wsw      = ws + 50331648;
  ushort_t* Wqkv = (ushort_t*)(wsw);                         // [288][96]
  ushort_t* Wo   = (ushort_t*)(wsw + 55296);                 // [96][96]
  ushort_t* W1   = (ushort_t*)(wsw + 55296 + 18432);         // [384][96]
  ushort_t* W2   = (ushort_t*)(wsw + 55296 + 18432 + 73728); // [96][384]
  float*    biasq= (float*)   (wsw + 55296 + 18432 + 73728 + 73728); // [288] fp32

  prep_kernel<<<434, 256, 0, stream>>>(wq, wk, wv, wo, w1, w2, bq, bk, bv,
                                       Wqkv, Wo, W1, W2, biasq);
  fat_kernel<<<4096, 256, 0, stream>>>(x, ln1g, ln1b, Wqkv, biasq, Wo, bo, x2b);
  mlp2_kernel<<<NTOK / 128, 256, 0, stream>>>(x2b, ln2g, ln2b, W1, b1, W2, b2, (float*)d_out);
}

// Round 22
// 173.567 us; speedup vs baseline: 1.0927x; 1.0927x over previous
//
#include <hip/hip_runtime.h>
#include <hip/hip_bf16.h>

typedef __attribute__((ext_vector_type(8))) short short8;
typedef __attribute__((ext_vector_type(4))) short short4b;
typedef __attribute__((ext_vector_type(4))) float f32x4;
typedef unsigned short ushort_t;

#define NTOK 262144   // B*D*H*W = 2*32*64*64

__device__ __forceinline__ ushort_t f2bf(float f){
  __hip_bfloat16 h = __float2bfloat16(f);
  return *reinterpret_cast<ushort_t*>(&h);
}
__device__ __forceinline__ float bf2f(ushort_t u){
  union { unsigned int i; float f; } v; v.i = ((unsigned int)u) << 16; return v.f;
}
// 1-instruction reciprocal (rel err ~2.5e-7)
__device__ __forceinline__ float fast_rcp(float x){
  float r; asm("v_rcp_f32 %0, %1" : "=v"(r) : "v"(x)); return r;
}
// sigmoid-form gelu: x * sigmoid(1.702x) (err <=0.005 for |x|<~1; our pre-act std ~0.2)
__device__ __forceinline__ float gelu_f(float x){
  float e = __expf(-1.702f * x);
  return x * fast_rcp(1.0f + e);
}
// LDS-only barrier: drains lgkm but NOT vmcnt.
__device__ __forceinline__ void bar_lds(){
  asm volatile("s_waitcnt lgkmcnt(0)" ::: "memory");
  __builtin_amdgcn_s_barrier();
  __builtin_amdgcn_sched_barrier(0);
}
// counted-vmcnt barriers (T4)
__device__ __forceinline__ void bar_cnt5(){
  asm volatile("s_waitcnt vmcnt(5) lgkmcnt(0)" ::: "memory");
  __builtin_amdgcn_s_barrier();
  __builtin_amdgcn_sched_barrier(0);
}
__device__ __forceinline__ void bar_cnt0(){
  asm volatile("s_waitcnt vmcnt(0) lgkmcnt(0)" ::: "memory");
  __builtin_amdgcn_s_barrier();
  __builtin_amdgcn_sched_barrier(0);
}
// async global->LDS, 16B per lane
__device__ __forceinline__ void gl_lds16(const ushort_t* g, ushort_t* l){
  __builtin_amdgcn_global_load_lds(
      (const __attribute__((address_space(1))) void*)g,
      (__attribute__((address_space(3))) void*)l, 16, 0, 0);
}

// stage a 48x96 half-slice into [48][104]-padded LDS (624 x 16B units; unit 12
// of each 13-unit row is pad, src = row start, never read). Full-drain use.
__device__ __forceinline__ void stage624(const ushort_t* __restrict__ src,
                                         ushort_t* __restrict__ dst, int tid)
{
  #pragma unroll
  for (int it = 0; it < 3; ++it) {
    int u = tid + it * 256;
    if (u < 624) {
      int row = u / 13, c16 = u % 13;
      const ushort_t* sp = src + row * 96 + ((c16 == 12) ? 0 : c16 * 8);
      gl_lds16(sp, dst + (size_t)(u & ~63) * 8);
    }
  }
}

// mlp2: padded 1280-unit flat buffer (20480B), EXACTLY 5 loads/thread
__device__ __forceinline__ void stage_wp(const ushort_t* __restrict__ src,
                                         int src_stride, ushort_t* __restrict__ dst, int tid)
{
  #pragma unroll
  for (int it = 0; it < 5; ++it) {
    int u = tid + it * 256;
    int row = u / 13, c16 = u % 13;
    const ushort_t* sp = src + row * src_stride + ((c16 >= 12) ? 0 : c16 * 8);
    gl_lds16(sp, dst + (size_t)(u & ~63) * 8);
  }
}

// ---------------- weight prep: fp32 -> bf16, transposed; Q-scale folded ----------------
__global__ __launch_bounds__(256) void prep_kernel(
    const float* __restrict__ wq, const float* __restrict__ wk, const float* __restrict__ wv,
    const float* __restrict__ wo, const float* __restrict__ w1, const float* __restrict__ w2,
    const float* __restrict__ bq, const float* __restrict__ bk, const float* __restrict__ bv,
    ushort_t* __restrict__ Wqkv, ushort_t* __restrict__ Wo,
    ushort_t* __restrict__ W1, ushort_t* __restrict__ W2, float* __restrict__ biasq)
{
  const float qs = 0.20412414523193150818f;   // 1/sqrt(24)
  int i = blockIdx.x * 256 + threadIdx.x;
  if (i < 27648) {                       // Wqkv_t[j][c], j = s*96 + h*24 + d
    int j = i / 96, c = i % 96;
    int s = j / 96, rem = j % 96;
    const float* src = (s == 0) ? wq : (s == 1) ? wk : wv;
    float val = src[c * 96 + rem];
    if (s == 0) val *= qs;               // fold QK^T scale into Q
    Wqkv[j * 96 + c] = f2bf(val);
  } else if (i < 36864) {                // Wo_t[c][hd] = wo[hd][c]
    int ii = i - 27648;
    int c = ii / 96, hd = ii % 96;
    Wo[ii] = f2bf(wo[hd * 96 + c]);
  } else if (i < 73728) {                // W1_t[j][c] = w1[c][j]
    int ii = i - 36864;
    int j = ii / 96, c = ii % 96;
    W1[ii] = f2bf(w1[c * 384 + j]);
  } else if (i < 110592) {               // W2_t[c][j] = w2[j][c]
    int ii = i - 73728;
    int c = ii / 384, j = ii % 384;
    W2[ii] = f2bf(w2[j * 96 + c]);
  } else if (i < 110880) {               // combined qkv bias (fp32), Q part scaled
    int j = i - 110592;
    int s = j / 96, rem = j % 96;
    const float* src = (s == 0) ? bq : (s == 1) ? bk : bv;
    float val = src[rem];
    if (s == 0) val *= qs;
    biasq[j] = val;
  }
}

// ================= FUSED: LN1 + QKV + window attention + proj + residual =================
// LDS diet v2: 50,816 B (fits 3 blocks/CU even at 2KB alloc granularity).
// Layout (ushort offsets in SM[25408]):
//   0      : QK[64][200] (12,800)  | hbt[64][104] alias | O_lds[64][104] alias
//   0      : P heads [4][64 rows][64 cols, XOR-swz] span 16,384 (over dead QK+Ws)
//   12,800 : Ws half-slice [48][104]-padded (5,120)
//   17,920 : Vt[4][24][72] (6,912) + 576 tail pad (junk-row overreads for d>=24)
__global__ __launch_bounds__(256, 3) void fat_kernel(
    const float* __restrict__ x, const float* __restrict__ g, const float* __restrict__ b,
    const ushort_t* __restrict__ Wqkv, const float* __restrict__ biasq,
    const ushort_t* __restrict__ Wo, const float* __restrict__ bo,
    ushort_t* __restrict__ x2b)
{
  __shared__ ushort_t SM[25408];
  const int WS_OFF = 12800, VT_OFF = 17920;

  int tid = threadIdx.x;
  int bid = blockIdx.x;
  int n = (bid & 7) * 512 + (bid >> 3);    // bijective XCD swizzle
  int wq_ = n & 15, hq = (n >> 4) & 15, rest = n >> 8;
  int dq = rest & 7, bb_ = rest >> 3;
  int base = bb_ * 131072 + dq * 16384 + hq * 256 + wq_ * 4;
  #define TOK(s) (base + ((s) >> 4) * 4096 + (((s) >> 2) & 3) * 64 + ((s) & 3))

  stage624(Wqkv, SM + WS_OFF, tid);        // Wqkv half 0 flies under LN

  // ---- LN1: thread t -> slot t>>2, quarter t&3 (wave-private hbt rows) ----
  {
    int s = tid >> 2, qr = tid & 3;
    const float* xp = x + (size_t)TOK(s) * 96 + qr * 24;
    f32x4 v[6];
    float sm = 0.f, sq = 0.f;
    #pragma unroll
    for (int i = 0; i < 6; i++) {
      v[i] = *reinterpret_cast<const f32x4*>(xp + i * 4);
      #pragma unroll
      for (int j = 0; j < 4; j++) { sm += v[i][j]; sq += v[i][j] * v[i][j]; }
    }
    sm += __shfl_xor(sm, 1); sq += __shfl_xor(sq, 1);
    sm += __shfl_xor(sm, 2); sq += __shfl_xor(sq, 2);
    float mean = sm * (1.0f / 96.0f);
    float var  = sq * (1.0f / 96.0f) - mean * mean;
    float rstd = rsqrtf(var + 1e-5f);
    #pragma unroll
    for (int i8 = 0; i8 < 3; i8++) {
      short8 pk;
      #pragma unroll
      for (int j = 0; j < 8; j++) {
        int c = qr * 24 + i8 * 8 + j;
        pk[j] = (short)f2bf((v[(i8 * 8 + j) >> 2][(i8 * 8 + j) & 3] - mean) * rstd * g[c] + b[c]);
      }
      *reinterpret_cast<short8*>(&SM[s * 104 + qr * 24 + i8 * 8]) = pk;
    }
  }

  int w = tid >> 6, lane = tid & 63, g16 = lane >> 4, l15 = lane & 15;
  short8 af[3];                            // own-wave hbt rows (in-order LDS)
  #pragma unroll
  for (int ks = 0; ks < 3; ks++)
    af[ks] = *reinterpret_cast<const short8*>(&SM[(w * 16 + l15) * 104 + ks * 32 + g16 * 8]);
  bar_lds();                               // af loads done: QK region (aliases hbt) free

  // ---- QKV: 6 half-slice phases, single buffer, full drains (TLP covers) ----
  for (int hidx = 0; hidx < 6; ++hidx) {
    const ushort_t* buf = SM + WS_OFF;
    bar_cnt0();                            // half resident + prev epilogue visible
    f32x4 acc[3];
    #pragma unroll
    for (int jj = 0; jj < 3; jj++) acc[jj] = (f32x4){0.f, 0.f, 0.f, 0.f};
    __builtin_amdgcn_s_setprio(1);
    #pragma unroll
    for (int jj = 0; jj < 3; jj++)
      #pragma unroll
      for (int ks = 0; ks < 3; ks++) {
        short8 wfr = *reinterpret_cast<const short8*>(&buf[(jj * 16 + l15) * 104 + ks * 32 + g16 * 8]);
        acc[jj] = __builtin_amdgcn_mfma_f32_16x16x32_bf16(wfr, af[ks], acc[jj], 0, 0, 0);
      }
    __builtin_amdgcn_s_setprio(0);
    bar_lds();                             // all waves done reading this half
    if (hidx < 5) stage624(Wqkv + (size_t)(hidx + 1) * 4608, SM + WS_OFF, tid);
    int grp = hidx >> 1, half = hidx & 1;
    if (grp < 2) {
      #pragma unroll
      for (int jj = 0; jj < 3; jj++) {
        int c0 = grp * 96 + (half * 3 + jj) * 16 + g16 * 4;
        f32x4 bb4 = *reinterpret_cast<const f32x4*>(&biasq[c0]);
        unsigned lo = (unsigned)f2bf(acc[jj][0] + bb4[0]) | ((unsigned)f2bf(acc[jj][1] + bb4[1]) << 16);
        unsigned hi = (unsigned)f2bf(acc[jj][2] + bb4[2]) | ((unsigned)f2bf(acc[jj][3] + bb4[3]) << 16);
        uint2 pk; pk.x = lo; pk.y = hi;
        *reinterpret_cast<uint2*>(&SM[(w * 16 + l15) * 200 + c0]) = pk;
      }
    } else {
      #pragma unroll
      for (int jj = 0; jj < 3; jj++) {
        int c0 = (half * 3 + jj) * 16 + g16 * 4;
        f32x4 bb4 = *reinterpret_cast<const f32x4*>(&biasq[192 + c0]);
        #pragma unroll
        for (int r = 0; r < 4; r++) {
          int vcol = c0 + r;
          int h2 = vcol / 24, d2 = vcol - h2 * 24;
          SM[VT_OFF + h2 * 1728 + d2 * 72 + (w * 16 + l15)] = f2bf(acc[jj][r] + bb4[r]);
        }
      }
    }
  }
  bar_lds();                               // all QK/Vt epilogue writes visible

  // ---- attention: wave = head ----
  int h = w;
  short8 kf[4], qf[4];
  const short8 z8 = {0, 0, 0, 0, 0, 0, 0, 0};
  #pragma unroll
  for (int i = 0; i < 4; i++) {
    qf[i] = (g16 < 3) ? *(const short8*)&SM[(i * 16 + l15) * 200 + h * 24 + g16 * 8]      : z8;
    kf[i] = (g16 < 3) ? *(const short8*)&SM[(i * 16 + l15) * 200 + 96 + h * 24 + g16 * 8] : z8;
  }
  f32x4 st[4][4];
  __builtin_amdgcn_s_setprio(1);
  #pragma unroll
  for (int tm = 0; tm < 4; tm++)
    #pragma unroll
    for (int tn = 0; tn < 4; tn++)
      st[tm][tn] = __builtin_amdgcn_mfma_f32_16x16x32_bf16(kf[tm], qf[tn],
                    (f32x4){0.f, 0.f, 0.f, 0.f}, 0, 0, 0);
  __builtin_amdgcn_s_setprio(0);
  bar_lds();                               // all QK reads done: P region free

  // softmax + P writes (packed [64][64] per head, XOR-unit swizzle)
  #pragma unroll
  for (int tn = 0; tn < 4; tn++) {
    float m = st[0][tn][0];
    #pragma unroll
    for (int tm = 0; tm < 4; tm++)
      #pragma unroll
      for (int r = 0; r < 4; r++) m = fmaxf(m, st[tm][tn][r]);
    m = fmaxf(m, __shfl_xor(m, 16));
    m = fmaxf(m, __shfl_xor(m, 32));
    float sum = 0.f;
    #pragma unroll
    for (int tm = 0; tm < 4; tm++)
      #pragma unroll
      for (int r = 0; r < 4; r++) {
        float e = __expf(st[tm][tn][r] - m);
        st[tm][tn][r] = e;
        sum += e;
      }
    sum += __shfl_xor(sum, 16);
    sum += __shfl_xor(sum, 32);
    float inv = fast_rcp(sum);
    int q = tn * 16 + l15;
    #pragma unroll
    for (int tm = 0; tm < 4; tm++) {
      unsigned lo = (unsigned)f2bf(st[tm][tn][0] * inv) | ((unsigned)f2bf(st[tm][tn][1] * inv) << 16);
      unsigned hi = (unsigned)f2bf(st[tm][tn][2] * inv) | ((unsigned)f2bf(st[tm][tn][3] * inv) << 16);
      uint2 pk; pk.x = lo; pk.y = hi;
      int u = tm * 2 + (g16 >> 1);         // 16B unit index 0..7
      *reinterpret_cast<uint2*>(&SM[h * 4096 + q * 64 + ((u ^ (q & 7)) << 3) + ((g16 & 1) << 2)]) = pk;
    }
  }

  // ---- O = P @ V (own-head P just written by this wave; in-order LDS) ----
  f32x4 oacc[4][2];
  #pragma unroll
  for (int qt = 0; qt < 4; qt++)
    #pragma unroll
    for (int dt = 0; dt < 2; dt++) oacc[qt][dt] = (f32x4){0.f, 0.f, 0.f, 0.f};
  __builtin_amdgcn_s_setprio(1);
  #pragma unroll
  for (int ks = 0; ks < 2; ks++) {
    short8 vb[2];
    #pragma unroll
    for (int dt = 0; dt < 2; dt++)
      vb[dt] = *(const short8*)&SM[VT_OFF + h * 1728 + (dt * 16 + l15) * 72 + ks * 32 + g16 * 8];
    #pragma unroll
    for (int qt = 0; qt < 4; qt++) {
      int row = qt * 16 + l15;
      int up = ks * 4 + g16;
      short8 pa = *(const short8*)&SM[h * 4096 + row * 64 + ((up ^ (row & 7)) << 3)];
      #pragma unroll
      for (int dt = 0; dt < 2; dt++)
        oacc[qt][dt] = __builtin_amdgcn_mfma_f32_16x16x32_bf16(pa, vb[dt], oacc[qt][dt], 0, 0, 0);
    }
  }
  __builtin_amdgcn_s_setprio(0);

  bar_lds();                               // all P reads done: O/Ws regions free
  stage624(Wo, SM + WS_OFF, tid);          // Wo half 0 flies under O writes
  #pragma unroll
  for (int qt = 0; qt < 4; qt++)
    #pragma unroll
    for (int dt = 0; dt < 2; dt++) {
      int d = dt * 16 + l15;
      if (d < 24) {
        #pragma unroll
        for (int r = 0; r < 4; r++)
          SM[(qt * 16 + g16 * 4 + r) * 104 + h * 24 + d] = f2bf(oacc[qt][dt][r]);
      }
    }
  bar_cnt0();                              // O visible + Wo half 0 resident

  // ---- proj (swapped): lane = token, regs = 4 consecutive outcols ----
  f32x4 pacc[6];
  #pragma unroll
  for (int nt = 0; nt < 6; nt++) pacc[nt] = (f32x4){0.f, 0.f, 0.f, 0.f};
  __builtin_amdgcn_s_setprio(1);
  #pragma unroll
  for (int ks = 0; ks < 3; ks++) {
    short8 pa = *(const short8*)&SM[(w * 16 + l15) * 104 + ks * 32 + g16 * 8];
    #pragma unroll
    for (int nt = 0; nt < 3; nt++) {
      short8 wb = *reinterpret_cast<const short8*>(&SM[WS_OFF + (nt * 16 + l15) * 104 + ks * 32 + g16 * 8]);
      pacc[nt] = __builtin_amdgcn_mfma_f32_16x16x32_bf16(wb, pa, pacc[nt], 0, 0, 0);
    }
  }
  __builtin_amdgcn_s_setprio(0);
  bar_lds();                               // Wo half 0 reads done
  stage624(Wo + 4608, SM + WS_OFF, tid);   // Wo half 1
  bar_cnt0();                              // Wo half 1 resident
  __builtin_amdgcn_s_setprio(1);
  #pragma unroll
  for (int ks = 0; ks < 3; ks++) {
    short8 pa = *(const short8*)&SM[(w * 16 + l15) * 104 + ks * 32 + g16 * 8];
    #pragma unroll
    for (int nt = 0; nt < 3; nt++) {
      short8 wb = *reinterpret_cast<const short8*>(&SM[WS_OFF + (nt * 16 + l15) * 104 + ks * 32 + g16 * 8]);
      pacc[3 + nt] = __builtin_amdgcn_mfma_f32_16x16x32_bf16(wb, pa, pacc[3 + nt], 0, 0, 0);
    }
  }
  __builtin_amdgcn_s_setprio(0);
  {
    size_t t = (size_t)TOK(w * 16 + l15);
    #pragma unroll
    for (int nt = 0; nt < 6; nt++) {
      int c0 = nt * 16 + g16 * 4;
      f32x4 bo4 = *reinterpret_cast<const f32x4*>(&bo[c0]);
      f32x4 xr  = *reinterpret_cast<const f32x4*>(&x[t * 96 + c0]);
      float v0 = pacc[nt][0] + bo4[0] + xr[0];
      float v1 = pacc[nt][1] + bo4[1] + xr[1];
      float v2 = pacc[nt][2] + bo4[2] + xr[2];
      float v3 = pacc[nt][3] + bo4[3] + xr[3];
      unsigned lo = (unsigned)f2bf(v0) | ((unsigned)f2bf(v1) << 16);
      unsigned hi = (unsigned)f2bf(v2) | ((unsigned)f2bf(v3) << 16);
      uint2 pk; pk.x = lo; pk.y = hi;
      *reinterpret_cast<uint2*>(&x2b[t * 96 + c0]) = pk;
    }
  }
  #undef TOK
}

// ---- per-thread half-row LN (bf16 input) into LDS tile smem[128][104] ----
__device__ __forceinline__ void ln_to_lds_b(const ushort_t* __restrict__ xrow_base,
    const float* __restrict__ gg, const float* __restrict__ bb,
    ushort_t (*hbt)[104], int tid)
{
  int row = tid >> 1, half = tid & 1;
  const ushort_t* xp = xrow_base + (size_t)row * 96 + half * 48;
  short8 vv[6];
  #pragma unroll
  for (int i = 0; i < 6; i++) vv[i] = *reinterpret_cast<const short8*>(xp + i * 8);
  float v[48];
  float s = 0.f, sq = 0.f;
  #pragma unroll
  for (int i = 0; i < 6; i++)
    #pragma unroll
    for (int j = 0; j < 8; j++) {
      float f = bf2f((ushort_t)vv[i][j]);
      v[i * 8 + j] = f; s += f; sq += f * f;
    }
  s  += __shfl_xor(s, 1);
  sq += __shfl_xor(sq, 1);
  float mean = s * (1.0f / 96.0f);
  float var  = sq * (1.0f / 96.0f) - mean * mean;
  float rstd = rsqrtf(var + 1e-5f);
  #pragma unroll
  for (int i8 = 0; i8 < 6; i8++) {
    short8 pk;
    #pragma unroll
    for (int j = 0; j < 8; j++) {
      int c = half * 48 + i8 * 8 + j;
      pk[j] = (short)f2bf((v[i8 * 8 + j] - mean) * rstd * gg[c] + bb[c]);
    }
    *reinterpret_cast<short8*>(&hbt[row][half * 48 + i8 * 8]) = pk;
  }
}

// ---------------- fused LN2 + MLP + residual: counted-vmcnt ping-pong (r16 winner) ----------------
__global__ __launch_bounds__(256, 2) void mlp2_kernel(
    const ushort_t* __restrict__ x2b, const float* __restrict__ g, const float* __restrict__ b,
    const ushort_t* __restrict__ W1t, const float* __restrict__ b1,
    const ushort_t* __restrict__ W2t, const float* __restrict__ b2,
    float* __restrict__ out)
{
  __shared__ ushort_t smem[128][104];   // LN rows, then mid (same storage) 26,624 B
  __shared__ ushort_t WsA[10240];       // W1 slice, padded to 1280 units (20,480 B)
  __shared__ ushort_t WsB[10240];       // W2 slice, padded (20,480 B)
  __shared__ float bias1[384];
  __shared__ float bias2[96];
  int tid = threadIdx.x;
  int bid = blockIdx.x;
  int blk = (bid & 7) * 256 + (bid >> 3);   // bijective XCD swizzle
  size_t r0 = (size_t)blk * 128;

  stage_wp(W1t, 96, WsA, tid);          // W1[0] -> A
  stage_wp(W2t, 384, WsB, tid);         // W2[0] -> B
  bias1[tid] = b1[tid];
  if (tid < 128) bias1[256 + tid] = b1[256 + tid];
  if (tid < 96)  bias2[tid] = b2[tid];
  ln_to_lds_b(x2b + r0 * 96, g, b, smem, tid);

  int w = tid >> 6, lane = tid & 63, g16 = lane >> 4, l15 = lane & 15;
  short8 af[2][3];
  #pragma unroll
  for (int mi = 0; mi < 2; mi++)
    #pragma unroll
    for (int ks = 0; ks < 3; ks++)
      af[mi][ks] = *reinterpret_cast<const short8*>(&smem[w * 32 + mi * 16 + l15][ks * 32 + g16 * 8]);
  __builtin_amdgcn_sched_barrier(0);

  f32x4 oacc[6][2];
  #pragma unroll
  for (int nt = 0; nt < 6; nt++) { oacc[nt][0] = (f32x4){0.f,0.f,0.f,0.f}; oacc[nt][1] = (f32x4){0.f,0.f,0.f,0.f}; }

  for (int cc = 0; cc < 4; ++cc) {
    bar_cnt5();                         // A = W1[cc] resident (B's 5 still in flight)
    f32x4 acc[6][2];
    #pragma unroll
    for (int nt = 0; nt < 6; nt++) { acc[nt][0] = (f32x4){0.f,0.f,0.f,0.f}; acc[nt][1] = (f32x4){0.f,0.f,0.f,0.f}; }
    __builtin_amdgcn_s_setprio(1);
    #pragma unroll
    for (int nt = 0; nt < 6; nt++)
      #pragma unroll
      for (int ks = 0; ks < 3; ks++) {
        short8 wfr = *reinterpret_cast<const short8*>(&WsA[(nt * 16 + l15) * 104 + ks * 32 + g16 * 8]);
        acc[nt][0] = __builtin_amdgcn_mfma_f32_16x16x32_bf16(wfr, af[0][ks], acc[nt][0], 0, 0, 0);
        acc[nt][1] = __builtin_amdgcn_mfma_f32_16x16x32_bf16(wfr, af[1][ks], acc[nt][1], 0, 0, 0);
      }
    __builtin_amdgcn_s_setprio(0);
    #pragma unroll
    for (int nt = 0; nt < 6; nt++) {
      f32x4 bb4 = *reinterpret_cast<const f32x4*>(&bias1[cc * 96 + nt * 16 + g16 * 4]);
      #pragma unroll
      for (int mi = 0; mi < 2; mi++) {
        float g0 = gelu_f(acc[nt][mi][0] + bb4[0]);
        float g1 = gelu_f(acc[nt][mi][1] + bb4[1]);
        float g2 = gelu_f(acc[nt][mi][2] + bb4[2]);
        float g3 = gelu_f(acc[nt][mi][3] + bb4[3]);
        unsigned lo = (unsigned)f2bf(g0) | ((unsigned)f2bf(g1) << 16);
        unsigned hi = (unsigned)f2bf(g2) | ((unsigned)f2bf(g3) << 16);
        uint2 pk; pk.x = lo; pk.y = hi;
        *reinterpret_cast<uint2*>(&smem[w * 32 + mi * 16 + l15][nt * 16 + g16 * 4]) = pk;
      }
    }
    short8 a2[2][3];
    #pragma unroll
    for (int mi = 0; mi < 2; mi++)
      #pragma unroll
      for (int ks = 0; ks < 3; ks++)
        a2[mi][ks] = *reinterpret_cast<const short8*>(&smem[w * 32 + mi * 16 + l15][ks * 32 + g16 * 8]);
    bar_lds();                          // all waves done reading A
    if (cc < 3) stage_wp(W1t + (cc + 1) * 9216, 96, WsA, tid);   // W1[cc+1] -> A
    if (cc < 3) bar_cnt5(); else bar_cnt0();   // B = W2[cc] resident (A' in flight)
    __builtin_amdgcn_s_setprio(1);
    #pragma unroll
    for (int nt = 0; nt < 6; nt++)
      #pragma unroll
      for (int ks = 0; ks < 3; ks++) {
        short8 wfr = *reinterpret_cast<const short8*>(&WsB[(nt * 16 + l15) * 104 + ks * 32 + g16 * 8]);
        oacc[nt][0] = __builtin_amdgcn_mfma_f32_16x16x32_bf16(wfr, a2[0][ks], oacc[nt][0], 0, 0, 0);
        oacc[nt][1] = __builtin_amdgcn_mfma_f32_16x16x32_bf16(wfr, a2[1][ks], oacc[nt][1], 0, 0, 0);
      }
    __builtin_amdgcn_s_setprio(0);
    if (cc < 3) {
      bar_lds();                        // all waves done reading B
      stage_wp(W2t + (cc + 1) * 96, 384, WsB, tid);              // W2[cc+1] -> B
    }
  }

  // epilogue: out = oacc + b2 + residual(x2b) (fp32 out)
  #pragma unroll
  for (int nt = 0; nt < 6; nt++) {
    int c0 = nt * 16 + g16 * 4;
    f32x4 bb4 = *reinterpret_cast<const f32x4*>(&bias2[c0]);
    #pragma unroll
    for (int mi = 0; mi < 2; mi++) {
      size_t row = r0 + w * 32 + mi * 16 + l15;
      short4b rr = *reinterpret_cast<const short4b*>(&x2b[row * 96 + c0]);
      f32x4 o;
      #pragma unroll
      for (int r = 0; r < 4; r++) o[r] = oacc[nt][mi][r] + bb4[r] + bf2f((ushort_t)rr[r]);
      *reinterpret_cast<f32x4*>(&out[row * 96 + c0]) = o;
    }
  }
}

// ---------------- launch ----------------
extern "C" void kernel_launch(void* const* d_in, const int* in_sizes, int n_in,
                              void* d_out, int out_size, void* d_ws, size_t ws_size,
                              hipStream_t stream)
{
  (void)in_sizes; (void)n_in; (void)out_size; (void)ws_size;
  const float* x    = (const float*)d_in[0];
  const float* ln1g = (const float*)d_in[1];
  const float* ln1b = (const float*)d_in[2];
  const float* wq   = (const float*)d_in[3];
  const float* bq   = (const float*)d_in[4];
  const float* wk   = (const float*)d_in[5];
  const float* bk   = (const float*)d_in[6];
  const float* wv   = (const float*)d_in[7];
  const float* bv   = (const float*)d_in[8];
  const float* wo   = (const float*)d_in[9];
  const float* bo   = (const float*)d_in[10];
  const float* ln2g = (const float*)d_in[11];
  const float* ln2b = (const float*)d_in[12];
  const float* w1   = (const float*)d_in[13];
  const float* b1   = (const float*)d_in[14];
  const float* w2   = (const float*)d_in[15];
  const float* b2   = (const float*)d_in[16];

  char* ws = (char*)d_ws;
  ushort_t* x2b  = (ushort_t*)(ws);                          // [N,96] bf16  50,331,648 B
  char* wsw      = ws + 50331648;
  ushort_t* Wqkv = (ushort_t*)(wsw);                         // [288][96]
  ushort_t* Wo   = (ushort_t*)(wsw + 55296);                 // [96][96]
  ushort_t* W1   = (ushort_t*)(wsw + 55296 + 18432);         // [384][96]
  ushort_t* W2   = (ushort_t*)(wsw + 55296 + 18432 + 73728); // [96][384]
  float*    biasq= (float*)   (wsw + 55296 + 18432 + 73728 + 73728); // [288] fp32

  prep_kernel<<<434, 256, 0, stream>>>(wq, wk, wv, wo, w1, w2, bq, bk, bv,
                                       Wqkv, Wo, W1, W2, biasq);
  fat_kernel<<<4096, 256, 0, stream>>>(x, ln1g, ln1b, Wqkv, biasq, Wo, bo, x2b);
  mlp2_kernel<<<NTOK / 128, 256, 0, stream>>>(x2b, ln2g, ln2b, W1, b1, W2, b2, (float*)d_out);
}

// Round 23
// 172.203 us; speedup vs baseline: 1.1013x; 1.0079x over previous
//
#include <hip/hip_runtime.h>
#include <hip/hip_bf16.h>

typedef __attribute__((ext_vector_type(8))) short short8;
typedef __attribute__((ext_vector_type(4))) short short4b;
typedef __attribute__((ext_vector_type(4))) float f32x4;
typedef unsigned short ushort_t;

#define NTOK 262144   // B*D*H*W = 2*32*64*64

__device__ __forceinline__ ushort_t f2bf(float f){
  __hip_bfloat16 h = __float2bfloat16(f);
  return *reinterpret_cast<ushort_t*>(&h);
}
__device__ __forceinline__ float bf2f(ushort_t u){
  union { unsigned int i; float f; } v; v.i = ((unsigned int)u) << 16; return v.f;
}
// 1-instruction reciprocal (rel err ~2.5e-7)
__device__ __forceinline__ float fast_rcp(float x){
  float r; asm("v_rcp_f32 %0, %1" : "=v"(r) : "v"(x)); return r;
}
// sigmoid-form gelu: x * sigmoid(1.702x) (err <=0.005 for |x|<~1; our pre-act std ~0.2)
__device__ __forceinline__ float gelu_f(float x){
  float e = __expf(-1.702f * x);
  return x * fast_rcp(1.0f + e);
}
// LDS-only barrier: drains lgkm but NOT vmcnt.
__device__ __forceinline__ void bar_lds(){
  asm volatile("s_waitcnt lgkmcnt(0)" ::: "memory");
  __builtin_amdgcn_s_barrier();
  __builtin_amdgcn_sched_barrier(0);
}
__device__ __forceinline__ void bar_cnt0(){
  asm volatile("s_waitcnt vmcnt(0) lgkmcnt(0)" ::: "memory");
  __builtin_amdgcn_s_barrier();
  __builtin_amdgcn_sched_barrier(0);
}
// async global->LDS, 16B per lane
__device__ __forceinline__ void gl_lds16(const ushort_t* g, ushort_t* l){
  __builtin_amdgcn_global_load_lds(
      (const __attribute__((address_space(1))) void*)g,
      (__attribute__((address_space(3))) void*)l, 16, 0, 0);
}

// stage a 48x96 half-slice into [48][104]-padded LDS (624 x 16B units; unit 12
// of each 13-unit row is pad, src = row start, never read). Full-drain use.
__device__ __forceinline__ void stage624(const ushort_t* __restrict__ src,
                                         ushort_t* __restrict__ dst, int tid)
{
  #pragma unroll
  for (int it = 0; it < 3; ++it) {
    int u = tid + it * 256;
    if (u < 624) {
      int row = u / 13, c16 = u % 13;
      const ushort_t* sp = src + row * 96 + ((c16 == 12) ? 0 : c16 * 8);
      gl_lds16(sp, dst + (size_t)(u & ~63) * 8);
    }
  }
}

// mlp2: padded 1280-unit flat buffer (20480B), 5 loads/thread (full-drain use)
__device__ __forceinline__ void stage_wp(const ushort_t* __restrict__ src,
                                         int src_stride, ushort_t* __restrict__ dst, int tid)
{
  #pragma unroll
  for (int it = 0; it < 5; ++it) {
    int u = tid + it * 256;
    int row = u / 13, c16 = u % 13;
    const ushort_t* sp = src + row * src_stride + ((c16 >= 12) ? 0 : c16 * 8);
    gl_lds16(sp, dst + (size_t)(u & ~63) * 8);
  }
}

// ---------------- weight prep: fp32 -> bf16, transposed; Q-scale folded ----------------
__global__ __launch_bounds__(256) void prep_kernel(
    const float* __restrict__ wq, const float* __restrict__ wk, const float* __restrict__ wv,
    const float* __restrict__ wo, const float* __restrict__ w1, const float* __restrict__ w2,
    const float* __restrict__ bq, const float* __restrict__ bk, const float* __restrict__ bv,
    ushort_t* __restrict__ Wqkv, ushort_t* __restrict__ Wo,
    ushort_t* __restrict__ W1, ushort_t* __restrict__ W2, float* __restrict__ biasq)
{
  const float qs = 0.20412414523193150818f;   // 1/sqrt(24)
  int i = blockIdx.x * 256 + threadIdx.x;
  if (i < 27648) {                       // Wqkv_t[j][c], j = s*96 + h*24 + d
    int j = i / 96, c = i % 96;
    int s = j / 96, rem = j % 96;
    const float* src = (s == 0) ? wq : (s == 1) ? wk : wv;
    float val = src[c * 96 + rem];
    if (s == 0) val *= qs;               // fold QK^T scale into Q
    Wqkv[j * 96 + c] = f2bf(val);
  } else if (i < 36864) {                // Wo_t[c][hd] = wo[hd][c]
    int ii = i - 27648;
    int c = ii / 96, hd = ii % 96;
    Wo[ii] = f2bf(wo[hd * 96 + c]);
  } else if (i < 73728) {                // W1_t[j][c] = w1[c][j]
    int ii = i - 36864;
    int j = ii / 96, c = ii % 96;
    W1[ii] = f2bf(w1[c * 384 + j]);
  } else if (i < 110592) {               // W2_t[c][j] = w2[j][c]
    int ii = i - 73728;
    int c = ii / 384, j = ii % 384;
    W2[ii] = f2bf(w2[j * 96 + c]);
  } else if (i < 110880) {               // combined qkv bias (fp32), Q part scaled
    int j = i - 110592;
    int s = j / 96, rem = j % 96;
    const float* src = (s == 0) ? bq : (s == 1) ? bk : bv;
    float val = src[rem];
    if (s == 0) val *= qs;
    biasq[j] = val;
  }
}

// ================= FUSED: LN1 + QKV + window attention + proj + residual =================
// 50,816 B LDS -> 3 blocks/CU (r22 champion, frozen).
__global__ __launch_bounds__(256, 3) void fat_kernel(
    const float* __restrict__ x, const float* __restrict__ g, const float* __restrict__ b,
    const ushort_t* __restrict__ Wqkv, const float* __restrict__ biasq,
    const ushort_t* __restrict__ Wo, const float* __restrict__ bo,
    ushort_t* __restrict__ x2b)
{
  __shared__ ushort_t SM[25408];
  const int WS_OFF = 12800, VT_OFF = 17920;

  int tid = threadIdx.x;
  int bid = blockIdx.x;
  int n = (bid & 7) * 512 + (bid >> 3);    // bijective XCD swizzle
  int wq_ = n & 15, hq = (n >> 4) & 15, rest = n >> 8;
  int dq = rest & 7, bb_ = rest >> 3;
  int base = bb_ * 131072 + dq * 16384 + hq * 256 + wq_ * 4;
  #define TOK(s) (base + ((s) >> 4) * 4096 + (((s) >> 2) & 3) * 64 + ((s) & 3))

  stage624(Wqkv, SM + WS_OFF, tid);        // Wqkv half 0 flies under LN

  // ---- LN1: thread t -> slot t>>2, quarter t&3 (wave-private hbt rows) ----
  {
    int s = tid >> 2, qr = tid & 3;
    const float* xp = x + (size_t)TOK(s) * 96 + qr * 24;
    f32x4 v[6];
    float sm = 0.f, sq = 0.f;
    #pragma unroll
    for (int i = 0; i < 6; i++) {
      v[i] = *reinterpret_cast<const f32x4*>(xp + i * 4);
      #pragma unroll
      for (int j = 0; j < 4; j++) { sm += v[i][j]; sq += v[i][j] * v[i][j]; }
    }
    sm += __shfl_xor(sm, 1); sq += __shfl_xor(sq, 1);
    sm += __shfl_xor(sm, 2); sq += __shfl_xor(sq, 2);
    float mean = sm * (1.0f / 96.0f);
    float var  = sq * (1.0f / 96.0f) - mean * mean;
    float rstd = rsqrtf(var + 1e-5f);
    #pragma unroll
    for (int i8 = 0; i8 < 3; i8++) {
      short8 pk;
      #pragma unroll
      for (int j = 0; j < 8; j++) {
        int c = qr * 24 + i8 * 8 + j;
        pk[j] = (short)f2bf((v[(i8 * 8 + j) >> 2][(i8 * 8 + j) & 3] - mean) * rstd * g[c] + b[c]);
      }
      *reinterpret_cast<short8*>(&SM[s * 104 + qr * 24 + i8 * 8]) = pk;
    }
  }

  int w = tid >> 6, lane = tid & 63, g16 = lane >> 4, l15 = lane & 15;
  short8 af[3];                            // own-wave hbt rows (in-order LDS)
  #pragma unroll
  for (int ks = 0; ks < 3; ks++)
    af[ks] = *reinterpret_cast<const short8*>(&SM[(w * 16 + l15) * 104 + ks * 32 + g16 * 8]);
  bar_lds();                               // af loads done: QK region (aliases hbt) free

  // ---- QKV: 6 half-slice phases, single buffer, full drains (TLP covers) ----
  for (int hidx = 0; hidx < 6; ++hidx) {
    const ushort_t* buf = SM + WS_OFF;
    bar_cnt0();                            // half resident + prev epilogue visible
    f32x4 acc[3];
    #pragma unroll
    for (int jj = 0; jj < 3; jj++) acc[jj] = (f32x4){0.f, 0.f, 0.f, 0.f};
    __builtin_amdgcn_s_setprio(1);
    #pragma unroll
    for (int jj = 0; jj < 3; jj++)
      #pragma unroll
      for (int ks = 0; ks < 3; ks++) {
        short8 wfr = *reinterpret_cast<const short8*>(&buf[(jj * 16 + l15) * 104 + ks * 32 + g16 * 8]);
        acc[jj] = __builtin_amdgcn_mfma_f32_16x16x32_bf16(wfr, af[ks], acc[jj], 0, 0, 0);
      }
    __builtin_amdgcn_s_setprio(0);
    bar_lds();                             // all waves done reading this half
    if (hidx < 5) stage624(Wqkv + (size_t)(hidx + 1) * 4608, SM + WS_OFF, tid);
    int grp = hidx >> 1, half = hidx & 1;
    if (grp < 2) {
      #pragma unroll
      for (int jj = 0; jj < 3; jj++) {
        int c0 = grp * 96 + (half * 3 + jj) * 16 + g16 * 4;
        f32x4 bb4 = *reinterpret_cast<const f32x4*>(&biasq[c0]);
        unsigned lo = (unsigned)f2bf(acc[jj][0] + bb4[0]) | ((unsigned)f2bf(acc[jj][1] + bb4[1]) << 16);
        unsigned hi = (unsigned)f2bf(acc[jj][2] + bb4[2]) | ((unsigned)f2bf(acc[jj][3] + bb4[3]) << 16);
        uint2 pk; pk.x = lo; pk.y = hi;
        *reinterpret_cast<uint2*>(&SM[(w * 16 + l15) * 200 + c0]) = pk;
      }
    } else {
      #pragma unroll
      for (int jj = 0; jj < 3; jj++) {
        int c0 = (half * 3 + jj) * 16 + g16 * 4;
        f32x4 bb4 = *reinterpret_cast<const f32x4*>(&biasq[192 + c0]);
        #pragma unroll
        for (int r = 0; r < 4; r++) {
          int vcol = c0 + r;
          int h2 = vcol / 24, d2 = vcol - h2 * 24;
          SM[VT_OFF + h2 * 1728 + d2 * 72 + (w * 16 + l15)] = f2bf(acc[jj][r] + bb4[r]);
        }
      }
    }
  }
  bar_lds();                               // all QK/Vt epilogue writes visible

  // ---- attention: wave = head ----
  int h = w;
  short8 kf[4], qf[4];
  const short8 z8 = {0, 0, 0, 0, 0, 0, 0, 0};
  #pragma unroll
  for (int i = 0; i < 4; i++) {
    qf[i] = (g16 < 3) ? *(const short8*)&SM[(i * 16 + l15) * 200 + h * 24 + g16 * 8]      : z8;
    kf[i] = (g16 < 3) ? *(const short8*)&SM[(i * 16 + l15) * 200 + 96 + h * 24 + g16 * 8] : z8;
  }
  f32x4 st[4][4];
  __builtin_amdgcn_s_setprio(1);
  #pragma unroll
  for (int tm = 0; tm < 4; tm++)
    #pragma unroll
    for (int tn = 0; tn < 4; tn++)
      st[tm][tn] = __builtin_amdgcn_mfma_f32_16x16x32_bf16(kf[tm], qf[tn],
                    (f32x4){0.f, 0.f, 0.f, 0.f}, 0, 0, 0);
  __builtin_amdgcn_s_setprio(0);
  bar_lds();                               // all QK reads done: P region free

  // softmax + P writes (packed [64][64] per head, XOR-unit swizzle)
  #pragma unroll
  for (int tn = 0; tn < 4; tn++) {
    float m = st[0][tn][0];
    #pragma unroll
    for (int tm = 0; tm < 4; tm++)
      #pragma unroll
      for (int r = 0; r < 4; r++) m = fmaxf(m, st[tm][tn][r]);
    m = fmaxf(m, __shfl_xor(m, 16));
    m = fmaxf(m, __shfl_xor(m, 32));
    float sum = 0.f;
    #pragma unroll
    for (int tm = 0; tm < 4; tm++)
      #pragma unroll
      for (int r = 0; r < 4; r++) {
        float e = __expf(st[tm][tn][r] - m);
        st[tm][tn][r] = e;
        sum += e;
      }
    sum += __shfl_xor(sum, 16);
    sum += __shfl_xor(sum, 32);
    float inv = fast_rcp(sum);
    int q = tn * 16 + l15;
    #pragma unroll
    for (int tm = 0; tm < 4; tm++) {
      unsigned lo = (unsigned)f2bf(st[tm][tn][0] * inv) | ((unsigned)f2bf(st[tm][tn][1] * inv) << 16);
      unsigned hi = (unsigned)f2bf(st[tm][tn][2] * inv) | ((unsigned)f2bf(st[tm][tn][3] * inv) << 16);
      uint2 pk; pk.x = lo; pk.y = hi;
      int u = tm * 2 + (g16 >> 1);         // 16B unit index 0..7
      *reinterpret_cast<uint2*>(&SM[h * 4096 + q * 64 + ((u ^ (q & 7)) << 3) + ((g16 & 1) << 2)]) = pk;
    }
  }

  // ---- O = P @ V (own-head P just written by this wave; in-order LDS) ----
  f32x4 oacc[4][2];
  #pragma unroll
  for (int qt = 0; qt < 4; qt++)
    #pragma unroll
    for (int dt = 0; dt < 2; dt++) oacc[qt][dt] = (f32x4){0.f, 0.f, 0.f, 0.f};
  __builtin_amdgcn_s_setprio(1);
  #pragma unroll
  for (int ks = 0; ks < 2; ks++) {
    short8 vb[2];
    #pragma unroll
    for (int dt = 0; dt < 2; dt++)
      vb[dt] = *(const short8*)&SM[VT_OFF + h * 1728 + (dt * 16 + l15) * 72 + ks * 32 + g16 * 8];
    #pragma unroll
    for (int qt = 0; qt < 4; qt++) {
      int row = qt * 16 + l15;
      int up = ks * 4 + g16;
      short8 pa = *(const short8*)&SM[h * 4096 + row * 64 + ((up ^ (row & 7)) << 3)];
      #pragma unroll
      for (int dt = 0; dt < 2; dt++)
        oacc[qt][dt] = __builtin_amdgcn_mfma_f32_16x16x32_bf16(pa, vb[dt], oacc[qt][dt], 0, 0, 0);
    }
  }
  __builtin_amdgcn_s_setprio(0);

  bar_lds();                               // all P reads done: O/Ws regions free
  stage624(Wo, SM + WS_OFF, tid);          // Wo half 0 flies under O writes
  #pragma unroll
  for (int qt = 0; qt < 4; qt++)
    #pragma unroll
    for (int dt = 0; dt < 2; dt++) {
      int d = dt * 16 + l15;
      if (d < 24) {
        #pragma unroll
        for (int r = 0; r < 4; r++)
          SM[(qt * 16 + g16 * 4 + r) * 104 + h * 24 + d] = f2bf(oacc[qt][dt][r]);
      }
    }
  bar_cnt0();                              // O visible + Wo half 0 resident

  // ---- proj (swapped): lane = token, regs = 4 consecutive outcols ----
  f32x4 pacc[6];
  #pragma unroll
  for (int nt = 0; nt < 6; nt++) pacc[nt] = (f32x4){0.f, 0.f, 0.f, 0.f};
  __builtin_amdgcn_s_setprio(1);
  #pragma unroll
  for (int ks = 0; ks < 3; ks++) {
    short8 pa = *(const short8*)&SM[(w * 16 + l15) * 104 + ks * 32 + g16 * 8];
    #pragma unroll
    for (int nt = 0; nt < 3; nt++) {
      short8 wb = *reinterpret_cast<const short8*>(&SM[WS_OFF + (nt * 16 + l15) * 104 + ks * 32 + g16 * 8]);
      pacc[nt] = __builtin_amdgcn_mfma_f32_16x16x32_bf16(wb, pa, pacc[nt], 0, 0, 0);
    }
  }
  __builtin_amdgcn_s_setprio(0);
  bar_lds();                               // Wo half 0 reads done
  stage624(Wo + 4608, SM + WS_OFF, tid);   // Wo half 1
  bar_cnt0();                              // Wo half 1 resident
  __builtin_amdgcn_s_setprio(1);
  #pragma unroll
  for (int ks = 0; ks < 3; ks++) {
    short8 pa = *(const short8*)&SM[(w * 16 + l15) * 104 + ks * 32 + g16 * 8];
    #pragma unroll
    for (int nt = 0; nt < 3; nt++) {
      short8 wb = *reinterpret_cast<const short8*>(&SM[WS_OFF + (nt * 16 + l15) * 104 + ks * 32 + g16 * 8]);
      pacc[3 + nt] = __builtin_amdgcn_mfma_f32_16x16x32_bf16(wb, pa, pacc[3 + nt], 0, 0, 0);
    }
  }
  __builtin_amdgcn_s_setprio(0);
  {
    size_t t = (size_t)TOK(w * 16 + l15);
    #pragma unroll
    for (int nt = 0; nt < 6; nt++) {
      int c0 = nt * 16 + g16 * 4;
      f32x4 bo4 = *reinterpret_cast<const f32x4*>(&bo[c0]);
      f32x4 xr  = *reinterpret_cast<const f32x4*>(&x[t * 96 + c0]);
      float v0 = pacc[nt][0] + bo4[0] + xr[0];
      float v1 = pacc[nt][1] + bo4[1] + xr[1];
      float v2 = pacc[nt][2] + bo4[2] + xr[2];
      float v3 = pacc[nt][3] + bo4[3] + xr[3];
      unsigned lo = (unsigned)f2bf(v0) | ((unsigned)f2bf(v1) << 16);
      unsigned hi = (unsigned)f2bf(v2) | ((unsigned)f2bf(v3) << 16);
      uint2 pk; pk.x = lo; pk.y = hi;
      *reinterpret_cast<uint2*>(&x2b[t * 96 + c0]) = pk;
    }
  }
  #undef TOK
}

// ---- per-thread half-row LN (bf16 input) into LDS tile smem[128][104] ----
__device__ __forceinline__ void ln_to_lds_b(const ushort_t* __restrict__ xrow_base,
    const float* __restrict__ gg, const float* __restrict__ bb,
    ushort_t (*hbt)[104], int tid)
{
  int row = tid >> 1, half = tid & 1;
  const ushort_t* xp = xrow_base + (size_t)row * 96 + half * 48;
  short8 vv[6];
  #pragma unroll
  for (int i = 0; i < 6; i++) vv[i] = *reinterpret_cast<const short8*>(xp + i * 8);
  float v[48];
  float s = 0.f, sq = 0.f;
  #pragma unroll
  for (int i = 0; i < 6; i++)
    #pragma unroll
    for (int j = 0; j < 8; j++) {
      float f = bf2f((ushort_t)vv[i][j]);
      v[i * 8 + j] = f; s += f; sq += f * f;
    }
  s  += __shfl_xor(s, 1);
  sq += __shfl_xor(sq, 1);
  float mean = s * (1.0f / 96.0f);
  float var  = sq * (1.0f / 96.0f) - mean * mean;
  float rstd = rsqrtf(var + 1e-5f);
  #pragma unroll
  for (int i8 = 0; i8 < 6; i8++) {
    short8 pk;
    #pragma unroll
    for (int j = 0; j < 8; j++) {
      int c = half * 48 + i8 * 8 + j;
      pk[j] = (short)f2bf((v[i8 * 8 + j] - mean) * rstd * gg[c] + bb[c]);
    }
    *reinterpret_cast<short8*>(&hbt[row][half * 48 + i8 * 8]) = pk;
  }
}

// ---------------- fused LN2 + MLP + residual: SINGLE weight buffer, 3 blocks/CU ----------------
// smem 26,624 + Ws 20,480 + biases 1,920 = 49,024 B -> rounds to 49,152;
// 3 x 49,152 = 147,456 <= 163,840. Full drains, TLP covers (fat r22 pattern).
__global__ __launch_bounds__(256, 3) void mlp2_kernel(
    const ushort_t* __restrict__ x2b, const float* __restrict__ g, const float* __restrict__ b,
    const ushort_t* __restrict__ W1t, const float* __restrict__ b1,
    const ushort_t* __restrict__ W2t, const float* __restrict__ b2,
    float* __restrict__ out)
{
  __shared__ ushort_t smem[128][104];   // LN rows, then mid (same storage) 26,624 B
  __shared__ ushort_t Ws[10240];        // single weight slice (20,480 B)
  __shared__ float bias1[384];
  __shared__ float bias2[96];
  int tid = threadIdx.x;
  int bid = blockIdx.x;
  int blk = (bid & 7) * 256 + (bid >> 3);   // bijective XCD swizzle
  size_t r0 = (size_t)blk * 128;

  stage_wp(W1t, 96, Ws, tid);           // W1[0] flies under LN
  bias1[tid] = b1[tid];
  if (tid < 128) bias1[256 + tid] = b1[256 + tid];
  if (tid < 96)  bias2[tid] = b2[tid];
  ln_to_lds_b(x2b + r0 * 96, g, b, smem, tid);

  int w = tid >> 6, lane = tid & 63, g16 = lane >> 4, l15 = lane & 15;
  short8 af[2][3];                      // wave-private smem rows (in-order LDS)
  #pragma unroll
  for (int mi = 0; mi < 2; mi++)
    #pragma unroll
    for (int ks = 0; ks < 3; ks++)
      af[mi][ks] = *reinterpret_cast<const short8*>(&smem[w * 32 + mi * 16 + l15][ks * 32 + g16 * 8]);
  __builtin_amdgcn_sched_barrier(0);

  f32x4 oacc[6][2];
  #pragma unroll
  for (int nt = 0; nt < 6; nt++) { oacc[nt][0] = (f32x4){0.f,0.f,0.f,0.f}; oacc[nt][1] = (f32x4){0.f,0.f,0.f,0.f}; }

  for (int cc = 0; cc < 4; ++cc) {
    bar_cnt0();                         // W1[cc] resident (+ prev-iter LDS settled)
    f32x4 acc[6][2];
    #pragma unroll
    for (int nt = 0; nt < 6; nt++) { acc[nt][0] = (f32x4){0.f,0.f,0.f,0.f}; acc[nt][1] = (f32x4){0.f,0.f,0.f,0.f}; }
    __builtin_amdgcn_s_setprio(1);
    #pragma unroll
    for (int nt = 0; nt < 6; nt++)
      #pragma unroll
      for (int ks = 0; ks < 3; ks++) {
        short8 wfr = *reinterpret_cast<const short8*>(&Ws[(nt * 16 + l15) * 104 + ks * 32 + g16 * 8]);
        acc[nt][0] = __builtin_amdgcn_mfma_f32_16x16x32_bf16(wfr, af[0][ks], acc[nt][0], 0, 0, 0);
        acc[nt][1] = __builtin_amdgcn_mfma_f32_16x16x32_bf16(wfr, af[1][ks], acc[nt][1], 0, 0, 0);
      }
    __builtin_amdgcn_s_setprio(0);
    bar_lds();                          // all waves done reading W1[cc]
    stage_wp(W2t + cc * 96, 384, Ws, tid);   // W2[cc] DMA flies under gelu/mid
    #pragma unroll
    for (int nt = 0; nt < 6; nt++) {
      f32x4 bb4 = *reinterpret_cast<const f32x4*>(&bias1[cc * 96 + nt * 16 + g16 * 4]);
      #pragma unroll
      for (int mi = 0; mi < 2; mi++) {
        float g0 = gelu_f(acc[nt][mi][0] + bb4[0]);
        float g1 = gelu_f(acc[nt][mi][1] + bb4[1]);
        float g2 = gelu_f(acc[nt][mi][2] + bb4[2]);
        float g3 = gelu_f(acc[nt][mi][3] + bb4[3]);
        unsigned lo = (unsigned)f2bf(g0) | ((unsigned)f2bf(g1) << 16);
        unsigned hi = (unsigned)f2bf(g2) | ((unsigned)f2bf(g3) << 16);
        uint2 pk; pk.x = lo; pk.y = hi;
        *reinterpret_cast<uint2*>(&smem[w * 32 + mi * 16 + l15][nt * 16 + g16 * 4]) = pk;
      }
    }
    short8 a2[2][3];                    // own rows, per-wave in-order LDS
    #pragma unroll
    for (int mi = 0; mi < 2; mi++)
      #pragma unroll
      for (int ks = 0; ks < 3; ks++)
        a2[mi][ks] = *reinterpret_cast<const short8*>(&smem[w * 32 + mi * 16 + l15][ks * 32 + g16 * 8]);
    bar_cnt0();                         // W2[cc] resident
    __builtin_amdgcn_s_setprio(1);
    #pragma unroll
    for (int nt = 0; nt < 6; nt++)
      #pragma unroll
      for (int ks = 0; ks < 3; ks++) {
        short8 wfr = *reinterpret_cast<const short8*>(&Ws[(nt * 16 + l15) * 104 + ks * 32 + g16 * 8]);
        oacc[nt][0] = __builtin_amdgcn_mfma_f32_16x16x32_bf16(wfr, a2[0][ks], oacc[nt][0], 0, 0, 0);
        oacc[nt][1] = __builtin_amdgcn_mfma_f32_16x16x32_bf16(wfr, a2[1][ks], oacc[nt][1], 0, 0, 0);
      }
    __builtin_amdgcn_s_setprio(0);
    if (cc < 3) {
      bar_lds();                        // all waves done reading W2[cc]
      stage_wp(W1t + (cc + 1) * 9216, 96, Ws, tid);   // W1[cc+1]
    }
  }

  // epilogue: out = oacc + b2 + residual(x2b) (fp32 out)
  #pragma unroll
  for (int nt = 0; nt < 6; nt++) {
    int c0 = nt * 16 + g16 * 4;
    f32x4 bb4 = *reinterpret_cast<const f32x4*>(&bias2[c0]);
    #pragma unroll
    for (int mi = 0; mi < 2; mi++) {
      size_t row = r0 + w * 32 + mi * 16 + l15;
      short4b rr = *reinterpret_cast<const short4b*>(&x2b[row * 96 + c0]);
      f32x4 o;
      #pragma unroll
      for (int r = 0; r < 4; r++) o[r] = oacc[nt][mi][r] + bb4[r] + bf2f((ushort_t)rr[r]);
      *reinterpret_cast<f32x4*>(&out[row * 96 + c0]) = o;
    }
  }
}

// ---------------- launch ----------------
extern "C" void kernel_launch(void* const* d_in, const int* in_sizes, int n_in,
                              void* d_out, int out_size, void* d_ws, size_t ws_size,
                              hipStream_t stream)
{
  (void)in_sizes; (void)n_in; (void)out_size; (void)ws_size;
  const float* x    = (const float*)d_in[0];
  const float* ln1g = (const float*)d_in[1];
  const float* ln1b = (const float*)d_in[2];
  const float* wq   = (const float*)d_in[3];
  const float* bq   = (const float*)d_in[4];
  const float* wk   = (const float*)d_in[5];
  const float* bk   = (const float*)d_in[6];
  const float* wv   = (const float*)d_in[7];
  const float* bv   = (const float*)d_in[8];
  const float* wo   = (const float*)d_in[9];
  const float* bo   = (const float*)d_in[10];
  const float* ln2g = (const float*)d_in[11];
  const float* ln2b = (const float*)d_in[12];
  const float* w1   = (const float*)d_in[13];
  const float* b1   = (const float*)d_in[14];
  const float* w2   = (const float*)d_in[15];
  const float* b2   = (const float*)d_in[16];

  char* ws = (char*)d_ws;
  ushort_t* x2b  = (ushort_t*)(ws);                          // [N,96] bf16  50,331,648 B
  char* wsw      = ws + 50331648;
  ushort_t* Wqkv = (ushort_t*)(wsw);                         // [288][96]
  ushort_t* Wo   = (ushort_t*)(wsw + 55296);                 // [96][96]
  ushort_t* W1   = (ushort_t*)(wsw + 55296 + 18432);         // [384][96]
  ushort_t* W2   = (ushort_t*)(wsw + 55296 + 18432 + 73728); // [96][384]
  float*    biasq= (float*)   (wsw + 55296 + 18432 + 73728 + 73728); // [288] fp32

  prep_kernel<<<434, 256, 0, stream>>>(wq, wk, wv, wo, w1, w2, bq, bk, bv,
                                       Wqkv, Wo, W1, W2, biasq);
  fat_kernel<<<4096, 256, 0, stream>>>(x, ln1g, ln1b, Wqkv, biasq, Wo, bo, x2b);
  mlp2_kernel<<<NTOK / 128, 256, 0, stream>>>(x2b, ln2g, ln2b, W1, b1, W2, b2, (float*)d_out);
}

// Round 24
// 172.096 us; speedup vs baseline: 1.1020x; 1.0006x over previous
//
#include <hip/hip_runtime.h>
#include <hip/hip_bf16.h>

typedef __attribute__((ext_vector_type(8))) short short8;
typedef __attribute__((ext_vector_type(4))) short short4b;
typedef __attribute__((ext_vector_type(4))) float f32x4;
typedef unsigned short ushort_t;

#define NTOK 262144   // B*D*H*W = 2*32*64*64

__device__ __forceinline__ ushort_t f2bf(float f){
  __hip_bfloat16 h = __float2bfloat16(f);
  return *reinterpret_cast<ushort_t*>(&h);
}
__device__ __forceinline__ float bf2f(ushort_t u){
  union { unsigned int i; float f; } v; v.i = ((unsigned int)u) << 16; return v.f;
}
// 1-instruction reciprocal (rel err ~2.5e-7)
__device__ __forceinline__ float fast_rcp(float x){
  float r; asm("v_rcp_f32 %0, %1" : "=v"(r) : "v"(x)); return r;
}
// sigmoid-form gelu: x * sigmoid(1.702x) (err <=0.005 for |x|<~1; our pre-act std ~0.2)
__device__ __forceinline__ float gelu_f(float x){
  float e = __expf(-1.702f * x);
  return x * fast_rcp(1.0f + e);
}
// LDS-only barrier: drains lgkm but NOT vmcnt.
__device__ __forceinline__ void bar_lds(){
  asm volatile("s_waitcnt lgkmcnt(0)" ::: "memory");
  __builtin_amdgcn_s_barrier();
  __builtin_amdgcn_sched_barrier(0);
}
__device__ __forceinline__ void bar_cnt0(){
  asm volatile("s_waitcnt vmcnt(0) lgkmcnt(0)" ::: "memory");
  __builtin_amdgcn_s_barrier();
  __builtin_amdgcn_sched_barrier(0);
}
// async global->LDS, 16B per lane
__device__ __forceinline__ void gl_lds16(const ushort_t* g, ushort_t* l){
  __builtin_amdgcn_global_load_lds(
      (const __attribute__((address_space(1))) void*)g,
      (__attribute__((address_space(3))) void*)l, 16, 0, 0);
}

// stage a 48x96 half-slice into [48][104]-padded LDS (624 x 16B units; unit 12
// of each 13-unit row is pad, src = row start, never read). Full-drain use.
__device__ __forceinline__ void stage624(const ushort_t* __restrict__ src,
                                         ushort_t* __restrict__ dst, int tid)
{
  #pragma unroll
  for (int it = 0; it < 3; ++it) {
    int u = tid + it * 256;
    if (u < 624) {
      int row = u / 13, c16 = u % 13;
      const ushort_t* sp = src + row * 96 + ((c16 == 12) ? 0 : c16 * 8);
      gl_lds16(sp, dst + (size_t)(u & ~63) * 8);
    }
  }
}

// padded 1280-unit flat [96+][104] stage (20480B), 5 loads/thread (full-drain use)
__device__ __forceinline__ void stage_wp(const ushort_t* __restrict__ src,
                                         int src_stride, ushort_t* __restrict__ dst, int tid)
{
  #pragma unroll
  for (int it = 0; it < 5; ++it) {
    int u = tid + it * 256;
    int row = u / 13, c16 = u % 13;
    const ushort_t* sp = src + row * src_stride + ((c16 >= 12) ? 0 : c16 * 8);
    gl_lds16(sp, dst + (size_t)(u & ~63) * 8);
  }
}

// ---------------- weight prep: fp32 -> bf16, transposed; Q-scale folded ----------------
__global__ __launch_bounds__(256) void prep_kernel(
    const float* __restrict__ wq, const float* __restrict__ wk, const float* __restrict__ wv,
    const float* __restrict__ wo, const float* __restrict__ w1, const float* __restrict__ w2,
    const float* __restrict__ bq, const float* __restrict__ bk, const float* __restrict__ bv,
    ushort_t* __restrict__ Wqkv, ushort_t* __restrict__ Wo,
    ushort_t* __restrict__ W1, ushort_t* __restrict__ W2, float* __restrict__ biasq)
{
  const float qs = 0.20412414523193150818f;   // 1/sqrt(24)
  int i = blockIdx.x * 256 + threadIdx.x;
  if (i < 27648) {                       // Wqkv_t[j][c], j = s*96 + h*24 + d
    int j = i / 96, c = i % 96;
    int s = j / 96, rem = j % 96;
    const float* src = (s == 0) ? wq : (s == 1) ? wk : wv;
    float val = src[c * 96 + rem];
    if (s == 0) val *= qs;               // fold QK^T scale into Q
    Wqkv[j * 96 + c] = f2bf(val);
  } else if (i < 36864) {                // Wo_t[c][hd] = wo[hd][c]
    int ii = i - 27648;
    int c = ii / 96, hd = ii % 96;
    Wo[ii] = f2bf(wo[hd * 96 + c]);
  } else if (i < 73728) {                // W1_t[j][c] = w1[c][j]
    int ii = i - 36864;
    int j = ii / 96, c = ii % 96;
    W1[ii] = f2bf(w1[c * 384 + j]);
  } else if (i < 110592) {               // W2_t[c][j] = w2[j][c]
    int ii = i - 73728;
    int c = ii / 384, j = ii % 384;
    W2[ii] = f2bf(w2[j * 96 + c]);
  } else if (i < 110880) {               // combined qkv bias (fp32), Q part scaled
    int j = i - 110592;
    int s = j / 96, rem = j % 96;
    const float* src = (s == 0) ? bq : (s == 1) ? bk : bv;
    float val = src[rem];
    if (s == 0) val *= qs;
    biasq[j] = val;
  }
}

// ================= FUSED: LN1 + QKV + window attention + proj + residual =================
// 50,816 B LDS -> 3 blocks/CU. Single half-slice weight buffer for QKV (full
// drains, TLP covers); post-PV the full Wo slice is staged ONCE into the dead
// P(heads2,3)+Ws region (offset 6,656) -> single proj MFMA block, fewer barriers.
__global__ __launch_bounds__(256, 3) void fat_kernel(
    const float* __restrict__ x, const float* __restrict__ g, const float* __restrict__ b,
    const ushort_t* __restrict__ Wqkv, const float* __restrict__ biasq,
    const ushort_t* __restrict__ Wo, const float* __restrict__ bo,
    ushort_t* __restrict__ x2b)
{
  __shared__ ushort_t SM[25408];
  const int WS_OFF = 12800, VT_OFF = 17920, WO_OFF = 6656;

  int tid = threadIdx.x;
  int bid = blockIdx.x;
  int n = (bid & 7) * 512 + (bid >> 3);    // bijective XCD swizzle
  int wq_ = n & 15, hq = (n >> 4) & 15, rest = n >> 8;
  int dq = rest & 7, bb_ = rest >> 3;
  int base = bb_ * 131072 + dq * 16384 + hq * 256 + wq_ * 4;
  #define TOK(s) (base + ((s) >> 4) * 4096 + (((s) >> 2) & 3) * 64 + ((s) & 3))

  stage624(Wqkv, SM + WS_OFF, tid);        // Wqkv half 0 flies under LN

  // ---- LN1: thread t -> slot t>>2, quarter t&3 (wave-private hbt rows) ----
  {
    int s = tid >> 2, qr = tid & 3;
    const float* xp = x + (size_t)TOK(s) * 96 + qr * 24;
    f32x4 v[6];
    float sm = 0.f, sq = 0.f;
    #pragma unroll
    for (int i = 0; i < 6; i++) {
      v[i] = *reinterpret_cast<const f32x4*>(xp + i * 4);
      #pragma unroll
      for (int j = 0; j < 4; j++) { sm += v[i][j]; sq += v[i][j] * v[i][j]; }
    }
    sm += __shfl_xor(sm, 1); sq += __shfl_xor(sq, 1);
    sm += __shfl_xor(sm, 2); sq += __shfl_xor(sq, 2);
    float mean = sm * (1.0f / 96.0f);
    float var  = sq * (1.0f / 96.0f) - mean * mean;
    float rstd = rsqrtf(var + 1e-5f);
    #pragma unroll
    for (int i8 = 0; i8 < 3; i8++) {
      short8 pk;
      #pragma unroll
      for (int j = 0; j < 8; j++) {
        int c = qr * 24 + i8 * 8 + j;
        pk[j] = (short)f2bf((v[(i8 * 8 + j) >> 2][(i8 * 8 + j) & 3] - mean) * rstd * g[c] + b[c]);
      }
      *reinterpret_cast<short8*>(&SM[s * 104 + qr * 24 + i8 * 8]) = pk;
    }
  }

  int w = tid >> 6, lane = tid & 63, g16 = lane >> 4, l15 = lane & 15;
  short8 af[3];                            // own-wave hbt rows (in-order LDS)
  #pragma unroll
  for (int ks = 0; ks < 3; ks++)
    af[ks] = *reinterpret_cast<const short8*>(&SM[(w * 16 + l15) * 104 + ks * 32 + g16 * 8]);
  bar_lds();                               // af loads done: QK region (aliases hbt) free

  // ---- QKV: 6 half-slice phases, single buffer, full drains (TLP covers) ----
  for (int hidx = 0; hidx < 6; ++hidx) {
    const ushort_t* buf = SM + WS_OFF;
    bar_cnt0();                            // half resident + prev epilogue visible
    f32x4 acc[3];
    #pragma unroll
    for (int jj = 0; jj < 3; jj++) acc[jj] = (f32x4){0.f, 0.f, 0.f, 0.f};
    __builtin_amdgcn_s_setprio(1);
    #pragma unroll
    for (int jj = 0; jj < 3; jj++)
      #pragma unroll
      for (int ks = 0; ks < 3; ks++) {
        short8 wfr = *reinterpret_cast<const short8*>(&buf[(jj * 16 + l15) * 104 + ks * 32 + g16 * 8]);
        acc[jj] = __builtin_amdgcn_mfma_f32_16x16x32_bf16(wfr, af[ks], acc[jj], 0, 0, 0);
      }
    __builtin_amdgcn_s_setprio(0);
    bar_lds();                             // all waves done reading this half
    if (hidx < 5) stage624(Wqkv + (size_t)(hidx + 1) * 4608, SM + WS_OFF, tid);
    int grp = hidx >> 1, half = hidx & 1;
    if (grp < 2) {
      #pragma unroll
      for (int jj = 0; jj < 3; jj++) {
        int c0 = grp * 96 + (half * 3 + jj) * 16 + g16 * 4;
        f32x4 bb4 = *reinterpret_cast<const f32x4*>(&biasq[c0]);
        unsigned lo = (unsigned)f2bf(acc[jj][0] + bb4[0]) | ((unsigned)f2bf(acc[jj][1] + bb4[1]) << 16);
        unsigned hi = (unsigned)f2bf(acc[jj][2] + bb4[2]) | ((unsigned)f2bf(acc[jj][3] + bb4[3]) << 16);
        uint2 pk; pk.x = lo; pk.y = hi;
        *reinterpret_cast<uint2*>(&SM[(w * 16 + l15) * 200 + c0]) = pk;
      }
    } else {
      #pragma unroll
      for (int jj = 0; jj < 3; jj++) {
        int c0 = (half * 3 + jj) * 16 + g16 * 4;
        f32x4 bb4 = *reinterpret_cast<const f32x4*>(&biasq[192 + c0]);
        #pragma unroll
        for (int r = 0; r < 4; r++) {
          int vcol = c0 + r;
          int h2 = vcol / 24, d2 = vcol - h2 * 24;
          SM[VT_OFF + h2 * 1728 + d2 * 72 + (w * 16 + l15)] = f2bf(acc[jj][r] + bb4[r]);
        }
      }
    }
  }
  bar_lds();                               // all QK/Vt epilogue writes visible

  // ---- attention: wave = head ----
  int h = w;
  short8 kf[4], qf[4];
  const short8 z8 = {0, 0, 0, 0, 0, 0, 0, 0};
  #pragma unroll
  for (int i = 0; i < 4; i++) {
    qf[i] = (g16 < 3) ? *(const short8*)&SM[(i * 16 + l15) * 200 + h * 24 + g16 * 8]      : z8;
    kf[i] = (g16 < 3) ? *(const short8*)&SM[(i * 16 + l15) * 200 + 96 + h * 24 + g16 * 8] : z8;
  }
  f32x4 st[4][4];
  __builtin_amdgcn_s_setprio(1);
  #pragma unroll
  for (int tm = 0; tm < 4; tm++)
    #pragma unroll
    for (int tn = 0; tn < 4; tn++)
      st[tm][tn] = __builtin_amdgcn_mfma_f32_16x16x32_bf16(kf[tm], qf[tn],
                    (f32x4){0.f, 0.f, 0.f, 0.f}, 0, 0, 0);
  __builtin_amdgcn_s_setprio(0);
  bar_lds();                               // all QK reads done: P region free

  // softmax + P writes (packed [64][64] per head, XOR-unit swizzle)
  #pragma unroll
  for (int tn = 0; tn < 4; tn++) {
    float m = st[0][tn][0];
    #pragma unroll
    for (int tm = 0; tm < 4; tm++)
      #pragma unroll
      for (int r = 0; r < 4; r++) m = fmaxf(m, st[tm][tn][r]);
    m = fmaxf(m, __shfl_xor(m, 16));
    m = fmaxf(m, __shfl_xor(m, 32));
    float sum = 0.f;
    #pragma unroll
    for (int tm = 0; tm < 4; tm++)
      #pragma unroll
      for (int r = 0; r < 4; r++) {
        float e = __expf(st[tm][tn][r] - m);
        st[tm][tn][r] = e;
        sum += e;
      }
    sum += __shfl_xor(sum, 16);
    sum += __shfl_xor(sum, 32);
    float inv = fast_rcp(sum);
    int q = tn * 16 + l15;
    #pragma unroll
    for (int tm = 0; tm < 4; tm++) {
      unsigned lo = (unsigned)f2bf(st[tm][tn][0] * inv) | ((unsigned)f2bf(st[tm][tn][1] * inv) << 16);
      unsigned hi = (unsigned)f2bf(st[tm][tn][2] * inv) | ((unsigned)f2bf(st[tm][tn][3] * inv) << 16);
      uint2 pk; pk.x = lo; pk.y = hi;
      int u = tm * 2 + (g16 >> 1);         // 16B unit index 0..7
      *reinterpret_cast<uint2*>(&SM[h * 4096 + q * 64 + ((u ^ (q & 7)) << 3) + ((g16 & 1) << 2)]) = pk;
    }
  }

  // ---- O = P @ V (own-head P just written by this wave; in-order LDS) ----
  f32x4 oacc[4][2];
  #pragma unroll
  for (int qt = 0; qt < 4; qt++)
    #pragma unroll
    for (int dt = 0; dt < 2; dt++) oacc[qt][dt] = (f32x4){0.f, 0.f, 0.f, 0.f};
  __builtin_amdgcn_s_setprio(1);
  #pragma unroll
  for (int ks = 0; ks < 2; ks++) {
    short8 vb[2];
    #pragma unroll
    for (int dt = 0; dt < 2; dt++)
      vb[dt] = *(const short8*)&SM[VT_OFF + h * 1728 + (dt * 16 + l15) * 72 + ks * 32 + g16 * 8];
    #pragma unroll
    for (int qt = 0; qt < 4; qt++) {
      int row = qt * 16 + l15;
      int up = ks * 4 + g16;
      short8 pa = *(const short8*)&SM[h * 4096 + row * 64 + ((up ^ (row & 7)) << 3)];
      #pragma unroll
      for (int dt = 0; dt < 2; dt++)
        oacc[qt][dt] = __builtin_amdgcn_mfma_f32_16x16x32_bf16(pa, vb[dt], oacc[qt][dt], 0, 0, 0);
    }
  }
  __builtin_amdgcn_s_setprio(0);

  bar_lds();                               // all P reads done: O dest + WO region free
  stage_wp(Wo, 96, SM + WO_OFF, tid);      // FULL Wo slice flies under O writes
  #pragma unroll
  for (int qt = 0; qt < 4; qt++)
    #pragma unroll
    for (int dt = 0; dt < 2; dt++) {
      int d = dt * 16 + l15;
      if (d < 24) {
        #pragma unroll
        for (int r = 0; r < 4; r++)
          SM[(qt * 16 + g16 * 4 + r) * 104 + h * 24 + d] = f2bf(oacc[qt][dt][r]);
      }
    }
  bar_cnt0();                              // O visible + full Wo resident

  // ---- proj (swapped): single MFMA block over all 6 outcol tiles ----
  f32x4 pacc[6];
  #pragma unroll
  for (int nt = 0; nt < 6; nt++) pacc[nt] = (f32x4){0.f, 0.f, 0.f, 0.f};
  __builtin_amdgcn_s_setprio(1);
  #pragma unroll
  for (int ks = 0; ks < 3; ks++) {
    short8 pa = *(const short8*)&SM[(w * 16 + l15) * 104 + ks * 32 + g16 * 8];
    #pragma unroll
    for (int nt = 0; nt < 6; nt++) {
      short8 wb = *reinterpret_cast<const short8*>(&SM[WO_OFF + (nt * 16 + l15) * 104 + ks * 32 + g16 * 8]);
      pacc[nt] = __builtin_amdgcn_mfma_f32_16x16x32_bf16(wb, pa, pacc[nt], 0, 0, 0);
    }
  }
  __builtin_amdgcn_s_setprio(0);
  {
    size_t t = (size_t)TOK(w * 16 + l15);
    #pragma unroll
    for (int nt = 0; nt < 6; nt++) {
      int c0 = nt * 16 + g16 * 4;
      f32x4 bo4 = *reinterpret_cast<const f32x4*>(&bo[c0]);
      f32x4 xr  = *reinterpret_cast<const f32x4*>(&x[t * 96 + c0]);
      float v0 = pacc[nt][0] + bo4[0] + xr[0];
      float v1 = pacc[nt][1] + bo4[1] + xr[1];
      float v2 = pacc[nt][2] + bo4[2] + xr[2];
      float v3 = pacc[nt][3] + bo4[3] + xr[3];
      unsigned lo = (unsigned)f2bf(v0) | ((unsigned)f2bf(v1) << 16);
      unsigned hi = (unsigned)f2bf(v2) | ((unsigned)f2bf(v3) << 16);
      uint2 pk; pk.x = lo; pk.y = hi;
      *reinterpret_cast<uint2*>(&x2b[t * 96 + c0]) = pk;
    }
  }
  #undef TOK
}

// ---- per-thread half-row LN (bf16 input) into LDS tile smem[128][104] ----
__device__ __forceinline__ void ln_to_lds_b(const ushort_t* __restrict__ xrow_base,
    const float* __restrict__ gg, const float* __restrict__ bb,
    ushort_t (*hbt)[104], int tid)
{
  int row = tid >> 1, half = tid & 1;
  const ushort_t* xp = xrow_base + (size_t)row * 96 + half * 48;
  short8 vv[6];
  #pragma unroll
  for (int i = 0; i < 6; i++) vv[i] = *reinterpret_cast<const short8*>(xp + i * 8);
  float v[48];
  float s = 0.f, sq = 0.f;
  #pragma unroll
  for (int i = 0; i < 6; i++)
    #pragma unroll
    for (int j = 0; j < 8; j++) {
      float f = bf2f((ushort_t)vv[i][j]);
      v[i * 8 + j] = f; s += f; sq += f * f;
    }
  s  += __shfl_xor(s, 1);
  sq += __shfl_xor(sq, 1);
  float mean = s * (1.0f / 96.0f);
  float var  = sq * (1.0f / 96.0f) - mean * mean;
  float rstd = rsqrtf(var + 1e-5f);
  #pragma unroll
  for (int i8 = 0; i8 < 6; i8++) {
    short8 pk;
    #pragma unroll
    for (int j = 0; j < 8; j++) {
      int c = half * 48 + i8 * 8 + j;
      pk[j] = (short)f2bf((v[i8 * 8 + j] - mean) * rstd * gg[c] + bb[c]);
    }
    *reinterpret_cast<short8*>(&hbt[row][half * 48 + i8 * 8]) = pk;
  }
}

// ---------------- fused LN2 + MLP + residual: SINGLE weight buffer, 3 blocks/CU (r23) ----------------
__global__ __launch_bounds__(256, 3) void mlp2_kernel(
    const ushort_t* __restrict__ x2b, const float* __restrict__ g, const float* __restrict__ b,
    const ushort_t* __restrict__ W1t, const float* __restrict__ b1,
    const ushort_t* __restrict__ W2t, const float* __restrict__ b2,
    float* __restrict__ out)
{
  __shared__ ushort_t smem[128][104];   // LN rows, then mid (same storage) 26,624 B
  __shared__ ushort_t Ws[10240];        // single weight slice (20,480 B)
  __shared__ float bias1[384];
  __shared__ float bias2[96];
  int tid = threadIdx.x;
  int bid = blockIdx.x;
  int blk = (bid & 7) * 256 + (bid >> 3);   // bijective XCD swizzle
  size_t r0 = (size_t)blk * 128;

  stage_wp(W1t, 96, Ws, tid);           // W1[0] flies under LN
  bias1[tid] = b1[tid];
  if (tid < 128) bias1[256 + tid] = b1[256 + tid];
  if (tid < 96)  bias2[tid] = b2[tid];
  ln_to_lds_b(x2b + r0 * 96, g, b, smem, tid);

  int w = tid >> 6, lane = tid & 63, g16 = lane >> 4, l15 = lane & 15;
  short8 af[2][3];                      // wave-private smem rows (in-order LDS)
  #pragma unroll
  for (int mi = 0; mi < 2; mi++)
    #pragma unroll
    for (int ks = 0; ks < 3; ks++)
      af[mi][ks] = *reinterpret_cast<const short8*>(&smem[w * 32 + mi * 16 + l15][ks * 32 + g16 * 8]);
  __builtin_amdgcn_sched_barrier(0);

  f32x4 oacc[6][2];
  #pragma unroll
  for (int nt = 0; nt < 6; nt++) { oacc[nt][0] = (f32x4){0.f,0.f,0.f,0.f}; oacc[nt][1] = (f32x4){0.f,0.f,0.f,0.f}; }

  for (int cc = 0; cc < 4; ++cc) {
    bar_cnt0();                         // W1[cc] resident (+ prev-iter LDS settled)
    f32x4 acc[6][2];
    #pragma unroll
    for (int nt = 0; nt < 6; nt++) { acc[nt][0] = (f32x4){0.f,0.f,0.f,0.f}; acc[nt][1] = (f32x4){0.f,0.f,0.f,0.f}; }
    __builtin_amdgcn_s_setprio(1);
    #pragma unroll
    for (int nt = 0; nt < 6; nt++)
      #pragma unroll
      for (int ks = 0; ks < 3; ks++) {
        short8 wfr = *reinterpret_cast<const short8*>(&Ws[(nt * 16 + l15) * 104 + ks * 32 + g16 * 8]);
        acc[nt][0] = __builtin_amdgcn_mfma_f32_16x16x32_bf16(wfr, af[0][ks], acc[nt][0], 0, 0, 0);
        acc[nt][1] = __builtin_amdgcn_mfma_f32_16x16x32_bf16(wfr, af[1][ks], acc[nt][1], 0, 0, 0);
      }
    __builtin_amdgcn_s_setprio(0);
    bar_lds();                          // all waves done reading W1[cc]
    stage_wp(W2t + cc * 96, 384, Ws, tid);   // W2[cc] DMA flies under gelu/mid
    #pragma unroll
    for (int nt = 0; nt < 6; nt++) {
      f32x4 bb4 = *reinterpret_cast<const f32x4*>(&bias1[cc * 96 + nt * 16 + g16 * 4]);
      #pragma unroll
      for (int mi = 0; mi < 2; mi++) {
        float g0 = gelu_f(acc[nt][mi][0] + bb4[0]);
        float g1 = gelu_f(acc[nt][mi][1] + bb4[1]);
        float g2 = gelu_f(acc[nt][mi][2] + bb4[2]);
        float g3 = gelu_f(acc[nt][mi][3] + bb4[3]);
        unsigned lo = (unsigned)f2bf(g0) | ((unsigned)f2bf(g1) << 16);
        unsigned hi = (unsigned)f2bf(g2) | ((unsigned)f2bf(g3) << 16);
        uint2 pk; pk.x = lo; pk.y = hi;
        *reinterpret_cast<uint2*>(&smem[w * 32 + mi * 16 + l15][nt * 16 + g16 * 4]) = pk;
      }
    }
    short8 a2[2][3];                    // own rows, per-wave in-order LDS
    #pragma unroll
    for (int mi = 0; mi < 2; mi++)
      #pragma unroll
      for (int ks = 0; ks < 3; ks++)
        a2[mi][ks] = *reinterpret_cast<const short8*>(&smem[w * 32 + mi * 16 + l15][ks * 32 + g16 * 8]);
    bar_cnt0();                         // W2[cc] resident
    __builtin_amdgcn_s_setprio(1);
    #pragma unroll
    for (int nt = 0; nt < 6; nt++)
      #pragma unroll
      for (int ks = 0; ks < 3; ks++) {
        short8 wfr = *reinterpret_cast<const short8*>(&Ws[(nt * 16 + l15) * 104 + ks * 32 + g16 * 8]);
        oacc[nt][0] = __builtin_amdgcn_mfma_f32_16x16x32_bf16(wfr, a2[0][ks], oacc[nt][0], 0, 0, 0);
        oacc[nt][1] = __builtin_amdgcn_mfma_f32_16x16x32_bf16(wfr, a2[1][ks], oacc[nt][1], 0, 0, 0);
      }
    __builtin_amdgcn_s_setprio(0);
    if (cc < 3) {
      bar_lds();                        // all waves done reading W2[cc]
      stage_wp(W1t + (cc + 1) * 9216, 96, Ws, tid);   // W1[cc+1]
    }
  }

  // epilogue: out = oacc + b2 + residual(x2b) (fp32 out)
  #pragma unroll
  for (int nt = 0; nt < 6; nt++) {
    int c0 = nt * 16 + g16 * 4;
    f32x4 bb4 = *reinterpret_cast<const f32x4*>(&bias2[c0]);
    #pragma unroll
    for (int mi = 0; mi < 2; mi++) {
      size_t row = r0 + w * 32 + mi * 16 + l15;
      short4b rr = *reinterpret_cast<const short4b*>(&x2b[row * 96 + c0]);
      f32x4 o;
      #pragma unroll
      for (int r = 0; r < 4; r++) o[r] = oacc[nt][mi][r] + bb4[r] + bf2f((ushort_t)rr[r]);
      *reinterpret_cast<f32x4*>(&out[row * 96 + c0]) = o;
    }
  }
}

// ---------------- launch ----------------
extern "C" void kernel_launch(void* const* d_in, const int* in_sizes, int n_in,
                              void* d_out, int out_size, void* d_ws, size_t ws_size,
                              hipStream_t stream)
{
  (void)in_sizes; (void)n_in; (void)out_size; (void)ws_size;
  const float* x    = (const float*)d_in[0];
  const float* ln1g = (const float*)d_in[1];
  const float* ln1b = (const float*)d_in[2];
  const float* wq   = (const float*)d_in[3];
  const float* bq   = (const float*)d_in[4];
  const float* wk   = (const float*)d_in[5];
  const float* bk   = (const float*)d_in[6];
  const float* wv   = (const float*)d_in[7];
  const float* bv   = (const float*)d_in[8];
  const float* wo   = (const float*)d_in[9];
  const float* bo   = (const float*)d_in[10];
  const float* ln2g = (const float*)d_in[11];
  const float* ln2b = (const float*)d_in[12];
  const float* w1   = (const float*)d_in[13];
  const float* b1   = (const float*)d_in[14];
  const float* w2   = (const float*)d_in[15];
  const float* b2   = (const float*)d_in[16];

  char* ws = (char*)d_ws;
  ushort_t* x2b  = (ushort_t*)(ws);                          // [N,96] bf16  50,331,648 B
  char* wsw      = ws + 50331648;
  ushort_t* Wqkv = (ushort_t*)(wsw);                         // [288][96]
  ushort_t* Wo   = (ushort_t*)(wsw + 55296);                 // [96][96]
  ushort_t* W1   = (ushort_t*)(wsw + 55296 + 18432);         // [384][96]
  ushort_t* W2   = (ushort_t*)(wsw + 55296 + 18432 + 73728); // [96][384]
  float*    biasq= (float*)   (wsw + 55296 + 18432 + 73728 + 73728); // [288] fp32

  prep_kernel<<<434, 256, 0, stream>>>(wq, wk, wv, wo, w1, w2, bq, bk, bv,
                                       Wqkv, Wo, W1, W2, biasq);
  fat_kernel<<<4096, 256, 0, stream>>>(x, ln1g, ln1b, Wqkv, biasq, Wo, bo, x2b);
  mlp2_kernel<<<NTOK / 128, 256, 0, stream>>>(x2b, ln2g, ln2b, W1, b1, W2, b2, (float*)d_out);
}